// Round 1
// baseline (2956.863 us; speedup 1.0000x reference)
//
#include <hip/hip_runtime.h>

#define IN_C 512
#define OUT_C 128
#define BM 64
#define BK 32

static inline int cdiv(int a, int b) { return (a + b - 1) / b; }

__device__ __forceinline__ float atomAddF(float* p, float v) {
  return __hip_atomic_fetch_add(p, v, __ATOMIC_RELAXED, __HIP_MEMORY_SCOPE_AGENT);
}

__global__ __launch_bounds__(256) void zero_kernel(float* __restrict__ p, int n) {
  int i = blockIdx.x * 256 + threadIdx.x;
  if (i < n) p[i] = 0.0f;
}

__global__ __launch_bounds__(256) void deg_kernel(const int* __restrict__ dst,
                                                  float* __restrict__ deg, int E) {
  int e = blockIdx.x * 256 + threadIdx.x;
  if (e < E) atomAddF(&deg[dst[e]], 1.0f);
}

// deg -> dinv in place (self-loop adds 1, so always > 0)
__global__ __launch_bounds__(256) void dinv_kernel(float* __restrict__ deg, int n) {
  int i = blockIdx.x * 256 + threadIdx.x;
  if (i < n) deg[i] = rsqrtf(deg[i] + 1.0f);
}

// h[n][128] = x[n][512] @ W[512][128], fp32, LDS-tiled
__global__ __launch_bounds__(256) void gemm_kernel(const float* __restrict__ x,
                                                   const float* __restrict__ W,
                                                   float* __restrict__ h, int n) {
  __shared__ float xT[BK][BM + 4];   // transposed x tile, pad keeps 16B align (68*4=272)
  __shared__ float Bs[BK][OUT_C];

  const int tid = threadIdx.x;
  const int c = tid & 31;   // col group: cols c*4 .. c*4+3
  const int r = tid >> 5;   // row group: rows r*8 .. r*8+7
  const int row0 = blockIdx.x * BM;

  float acc[8][4];
#pragma unroll
  for (int i = 0; i < 8; i++)
#pragma unroll
    for (int j = 0; j < 4; j++) acc[i][j] = 0.0f;

  const int lrow = tid >> 2;       // 0..63 staging row
  const int lk = (tid & 3) * 8;    // 0,8,16,24 staging k-offset
  int grow = row0 + lrow;
  if (grow > n - 1) grow = n - 1;  // clamp (dup rows never stored)
  const float* xrow = x + (size_t)grow * IN_C;

  for (int k0 = 0; k0 < IN_C; k0 += BK) {
    float4 v0 = *(const float4*)(xrow + k0 + lk);
    float4 v1 = *(const float4*)(xrow + k0 + lk + 4);
    __syncthreads();
    xT[lk + 0][lrow] = v0.x; xT[lk + 1][lrow] = v0.y;
    xT[lk + 2][lrow] = v0.z; xT[lk + 3][lrow] = v0.w;
    xT[lk + 4][lrow] = v1.x; xT[lk + 5][lrow] = v1.y;
    xT[lk + 6][lrow] = v1.z; xT[lk + 7][lrow] = v1.w;
    const float4* wsrc = (const float4*)(W + (size_t)k0 * OUT_C);
    float4* bflat = (float4*)&Bs[0][0];
#pragma unroll
    for (int q = 0; q < 4; q++) bflat[tid + q * 256] = wsrc[tid + q * 256];
    __syncthreads();
#pragma unroll
    for (int k = 0; k < BK; k++) {
      float4 a0 = *(const float4*)&xT[k][r * 8];
      float4 a1 = *(const float4*)&xT[k][r * 8 + 4];
      float4 bb = *(const float4*)&Bs[k][c * 4];
      float av[8] = {a0.x, a0.y, a0.z, a0.w, a1.x, a1.y, a1.z, a1.w};
      float bv[4] = {bb.x, bb.y, bb.z, bb.w};
#pragma unroll
      for (int i = 0; i < 8; i++)
#pragma unroll
        for (int j = 0; j < 4; j++) acc[i][j] += av[i] * bv[j];
    }
  }

#pragma unroll
  for (int i = 0; i < 8; i++) {
    int row = row0 + r * 8 + i;
    if (row < n) {
      float4 o = make_float4(acc[i][0], acc[i][1], acc[i][2], acc[i][3]);
      *(float4*)(h + (size_t)row * OUT_C + c * 4) = o;
    }
  }
}

// out[i][:] = h[i][:] * dinv[i]^2 + b[:]; also zero the tail scalar output
__global__ __launch_bounds__(256) void self_bias_kernel(const float* __restrict__ h,
                                                        const float* __restrict__ dinv,
                                                        const float* __restrict__ b,
                                                        float* __restrict__ out,
                                                        int n, int tail) {
  int gid = blockIdx.x * 256 + threadIdx.x;  // one per 4 cols
  int total = n * (OUT_C / 4);
  if (gid < total) {
    int i = gid >> 5;
    int q = gid & 31;
    float di = dinv[i];
    float s = di * di;
    float4 hv = ((const float4*)h)[(size_t)i * 32 + q];
    float4 bv = ((const float4*)b)[q];
    float4 o;
    o.x = hv.x * s + bv.x;
    o.y = hv.y * s + bv.y;
    o.z = hv.z * s + bv.z;
    o.w = hv.w * s + bv.w;
    ((float4*)out)[(size_t)i * 32 + q] = o;
  }
  if (gid == 0) {
    for (int t = 0; t < tail; t++) out[(size_t)n * OUT_C + t] = 0.0f;
  }
}

// out[dst] += h[src] * dinv[src]*dinv[dst], 32 threads (x4 cols) per edge
__global__ __launch_bounds__(256) void scatter_kernel(const int* __restrict__ src,
                                                      const int* __restrict__ dst,
                                                      const float* __restrict__ h,
                                                      const float* __restrict__ dinv,
                                                      float* __restrict__ out, int E) {
  int gid = blockIdx.x * 256 + threadIdx.x;
  int e = gid >> 5;
  if (e >= E) return;
  int q = gid & 31;
  int s = src[e];
  int d = dst[e];
  float nrm = dinv[s] * dinv[d];
  float4 hv = ((const float4*)(h + (size_t)s * OUT_C))[q];
  float* op = out + (size_t)d * OUT_C + q * 4;
  atomAddF(op + 0, hv.x * nrm);
  atomAddF(op + 1, hv.y * nrm);
  atomAddF(op + 2, hv.z * nrm);
  atomAddF(op + 3, hv.w * nrm);
}

extern "C" void kernel_launch(void* const* d_in, const int* in_sizes, int n_in,
                              void* d_out, int out_size, void* d_ws, size_t ws_size,
                              hipStream_t stream) {
  const float* x = (const float*)d_in[0];
  const int* ei = (const int*)d_in[1];
  const float* W = (const float*)d_in[2];
  const float* b = (const float*)d_in[3];

  const int n = in_sizes[0] / IN_C;
  const int E = in_sizes[1] / 2;
  const int* src = ei;
  const int* dst = ei + E;

  float* dinv = (float*)d_ws;
  size_t hoff = (((size_t)n * 4) + 255) & ~(size_t)255;
  float* h = (float*)((char*)d_ws + hoff);
  float* out = (float*)d_out;

  zero_kernel<<<cdiv(n, 256), 256, 0, stream>>>(dinv, n);
  deg_kernel<<<cdiv(E, 256), 256, 0, stream>>>(dst, dinv, E);
  dinv_kernel<<<cdiv(n, 256), 256, 0, stream>>>(dinv, n);
  gemm_kernel<<<cdiv(n, BM), 256, 0, stream>>>(x, W, h, n);
  int tail = out_size - n * OUT_C;
  self_bias_kernel<<<cdiv(n * (OUT_C / 4), 256), 256, 0, stream>>>(h, dinv, b, out, n, tail);
  scatter_kernel<<<cdiv(E * 32, 256), 256, 0, stream>>>(src, dst, h, dinv, out, E);
}

// Round 2
// 498.599 us; speedup vs baseline: 5.9303x; 5.9303x over previous
//
#include <hip/hip_runtime.h>

#define IN_C 512
#define OUT_C 128
#define BM 64
#define BK 32
#define SCAN_TILE 2048

static inline int cdiv(int a, int b) { return (a + b - 1) / b; }

__device__ __forceinline__ float atomAddF(float* p, float v) {
  return __hip_atomic_fetch_add(p, v, __ATOMIC_RELAXED, __HIP_MEMORY_SCOPE_AGENT);
}
__device__ __forceinline__ int atomAddI(int* p, int v) {
  return __hip_atomic_fetch_add(p, v, __ATOMIC_RELAXED, __HIP_MEMORY_SCOPE_AGENT);
}

__global__ __launch_bounds__(256) void zero_i_kernel(int* __restrict__ p, int n) {
  int i = blockIdx.x * 256 + threadIdx.x;
  if (i < n) p[i] = 0;
}

__global__ __launch_bounds__(256) void deg_kernel(const int* __restrict__ dst,
                                                  int* __restrict__ deg, int E) {
  int e = blockIdx.x * 256 + threadIdx.x;
  if (e < E) atomAddI(&deg[dst[e]], 1);
}

// dinv[i] = rsqrt(deg[i] + 1)  (self-loop included)
__global__ __launch_bounds__(256) void dinv_kernel(const int* __restrict__ deg,
                                                   float* __restrict__ dinv, int n) {
  int i = blockIdx.x * 256 + threadIdx.x;
  if (i < n) dinv[i] = rsqrtf((float)deg[i] + 1.0f);
}

// ---- 3-phase exclusive scan of deg -> offs ----
__global__ __launch_bounds__(256) void scan1_kernel(const int* __restrict__ deg,
                                                    int* __restrict__ offs,
                                                    int* __restrict__ bsums, int n) {
  __shared__ int sh[256];
  int t = threadIdx.x;
  int base = blockIdx.x * SCAN_TILE + t * 8;
  int v[8];
  int s = 0;
#pragma unroll
  for (int i = 0; i < 8; i++) {
    int idx = base + i;
    v[i] = (idx < n) ? deg[idx] : 0;
    s += v[i];
  }
  sh[t] = s;
  __syncthreads();
  for (int off = 1; off < 256; off <<= 1) {
    int x = sh[t];
    if (t >= off) x += sh[t - off];
    __syncthreads();
    sh[t] = x;
    __syncthreads();
  }
  int run = sh[t] - s;  // exclusive base for this thread
#pragma unroll
  for (int i = 0; i < 8; i++) {
    int idx = base + i;
    if (idx < n) offs[idx] = run;
    run += v[i];
  }
  if (t == 255) bsums[blockIdx.x] = sh[255];
}

__global__ __launch_bounds__(256) void scan2_kernel(int* __restrict__ bsums, int nb) {
  __shared__ int sh[256];
  int t = threadIdx.x;
  int v = (t < nb) ? bsums[t] : 0;
  sh[t] = v;
  __syncthreads();
  for (int off = 1; off < 256; off <<= 1) {
    int x = sh[t];
    if (t >= off) x += sh[t - off];
    __syncthreads();
    sh[t] = x;
    __syncthreads();
  }
  if (t < nb) bsums[t] = sh[t] - v;  // exclusive
}

__global__ __launch_bounds__(256) void scan3_kernel(int* __restrict__ offs,
                                                    int* __restrict__ cursor,
                                                    const int* __restrict__ bsums,
                                                    int n, int E) {
  int i = blockIdx.x * 256 + threadIdx.x;
  if (i < n) {
    int o = offs[i] + bsums[i >> 11];  // SCAN_TILE = 2048
    offs[i] = o;
    cursor[i] = o;
  }
  if (i == 0) offs[n] = E;
}

__global__ __launch_bounds__(256) void csr_kernel(const int* __restrict__ src,
                                                  const int* __restrict__ dst,
                                                  int* __restrict__ cursor,
                                                  int* __restrict__ csr_src, int E) {
  int e = blockIdx.x * 256 + threadIdx.x;
  if (e < E) {
    int pos = atomAddI(&cursor[dst[e]], 1);
    csr_src[pos] = src[e];
  }
}

// h[n][128] = x[n][512] @ W[512][128], fp32, LDS-tiled
__global__ __launch_bounds__(256) void gemm_kernel(const float* __restrict__ x,
                                                   const float* __restrict__ W,
                                                   float* __restrict__ h, int n) {
  __shared__ float xT[BK][BM + 4];
  __shared__ float Bs[BK][OUT_C];

  const int tid = threadIdx.x;
  const int c = tid & 31;
  const int r = tid >> 5;
  const int row0 = blockIdx.x * BM;

  float acc[8][4];
#pragma unroll
  for (int i = 0; i < 8; i++)
#pragma unroll
    for (int j = 0; j < 4; j++) acc[i][j] = 0.0f;

  const int lrow = tid >> 2;
  const int lk = (tid & 3) * 8;
  int grow = row0 + lrow;
  if (grow > n - 1) grow = n - 1;
  const float* xrow = x + (size_t)grow * IN_C;

  for (int k0 = 0; k0 < IN_C; k0 += BK) {
    float4 v0 = *(const float4*)(xrow + k0 + lk);
    float4 v1 = *(const float4*)(xrow + k0 + lk + 4);
    __syncthreads();
    xT[lk + 0][lrow] = v0.x; xT[lk + 1][lrow] = v0.y;
    xT[lk + 2][lrow] = v0.z; xT[lk + 3][lrow] = v0.w;
    xT[lk + 4][lrow] = v1.x; xT[lk + 5][lrow] = v1.y;
    xT[lk + 6][lrow] = v1.z; xT[lk + 7][lrow] = v1.w;
    const float4* wsrc = (const float4*)(W + (size_t)k0 * OUT_C);
    float4* bflat = (float4*)&Bs[0][0];
#pragma unroll
    for (int q = 0; q < 4; q++) bflat[tid + q * 256] = wsrc[tid + q * 256];
    __syncthreads();
#pragma unroll
    for (int k = 0; k < BK; k++) {
      float4 a0 = *(const float4*)&xT[k][r * 8];
      float4 a1 = *(const float4*)&xT[k][r * 8 + 4];
      float4 bb = *(const float4*)&Bs[k][c * 4];
      float av[8] = {a0.x, a0.y, a0.z, a0.w, a1.x, a1.y, a1.z, a1.w};
      float bv[4] = {bb.x, bb.y, bb.z, bb.w};
#pragma unroll
      for (int i = 0; i < 8; i++)
#pragma unroll
        for (int j = 0; j < 4; j++) acc[i][j] += av[i] * bv[j];
    }
  }

#pragma unroll
  for (int i = 0; i < 8; i++) {
    int row = row0 + r * 8 + i;
    if (row < n) {
      float4 o = make_float4(acc[i][0], acc[i][1], acc[i][2], acc[i][3]);
      *(float4*)(h + (size_t)row * OUT_C + c * 4) = o;
    }
  }
}

// One wave per node: out[d] = dinv[d]*(sum_e h[src_e]*dinv[src_e] + h[d]*dinv[d]) + b
__global__ __launch_bounds__(256) void gather_kernel(const int* __restrict__ offs,
                                                     const int* __restrict__ csr_src,
                                                     const float* __restrict__ h,
                                                     const float* __restrict__ dinv,
                                                     const float* __restrict__ b,
                                                     float* __restrict__ out,
                                                     int n, int tail) {
  int wid = threadIdx.x >> 6;
  int lane = threadIdx.x & 63;
  int node = blockIdx.x * 4 + wid;
  if (node >= n) return;

  int start = offs[node];
  int end = offs[node + 1];
  const float2* hp = (const float2*)h;  // row = 64 float2

  float accx = 0.0f, accy = 0.0f;
  int e = start;
  for (; e + 4 <= end; e += 4) {
    int s0 = csr_src[e + 0];
    int s1 = csr_src[e + 1];
    int s2 = csr_src[e + 2];
    int s3 = csr_src[e + 3];
    float w0 = dinv[s0], w1 = dinv[s1], w2 = dinv[s2], w3 = dinv[s3];
    float2 h0 = hp[(size_t)s0 * 64 + lane];
    float2 h1 = hp[(size_t)s1 * 64 + lane];
    float2 h2 = hp[(size_t)s2 * 64 + lane];
    float2 h3 = hp[(size_t)s3 * 64 + lane];
    accx += h0.x * w0 + h1.x * w1 + h2.x * w2 + h3.x * w3;
    accy += h0.y * w0 + h1.y * w1 + h2.y * w2 + h3.y * w3;
  }
  for (; e < end; e++) {
    int s = csr_src[e];
    float w = dinv[s];
    float2 hv = hp[(size_t)s * 64 + lane];
    accx += hv.x * w;
    accy += hv.y * w;
  }

  float dd = dinv[node];
  float2 hs = hp[(size_t)node * 64 + lane];
  accx = (accx + hs.x * dd) * dd;
  accy = (accy + hs.y * dd) * dd;
  float2 bb = ((const float2*)b)[lane];
  accx += bb.x;
  accy += bb.y;
  float2 o = make_float2(accx, accy);
  ((float2*)out)[(size_t)node * 64 + lane] = o;

  if (node == 0 && lane == 0) {
    for (int t = 0; t < tail; t++) out[(size_t)n * OUT_C + t] = 0.0f;
  }
}

extern "C" void kernel_launch(void* const* d_in, const int* in_sizes, int n_in,
                              void* d_out, int out_size, void* d_ws, size_t ws_size,
                              hipStream_t stream) {
  const float* x = (const float*)d_in[0];
  const int* ei = (const int*)d_in[1];
  const float* W = (const float*)d_in[2];
  const float* b = (const float*)d_in[3];

  const int n = in_sizes[0] / IN_C;
  const int E = in_sizes[1] / 2;
  const int* src = ei;
  const int* dst = ei + E;
  float* out = (float*)d_out;

  // workspace layout (256B-aligned slabs)
  size_t p = 0;
  auto alloc = [&](size_t bytes) { size_t o = p; p += (bytes + 255) & ~(size_t)255; return o; };
  char* ws = (char*)d_ws;
  float* dinv   = (float*)(ws + alloc((size_t)n * 4));
  float* h      = (float*)(ws + alloc((size_t)n * OUT_C * 4));
  int*   offs   = (int*)  (ws + alloc(((size_t)n + 1) * 4));
  int*   csrsrc = (int*)  (ws + alloc((size_t)E * 4));
  int*   deg    = (int*)  (ws + alloc((size_t)n * 4));   // reused as cursor
  int*   bsums  = (int*)  (ws + alloc(256 * 4));
  int*   cursor = deg;

  const int nb = cdiv(n, SCAN_TILE);

  zero_i_kernel<<<cdiv(n, 256), 256, 0, stream>>>(deg, n);
  deg_kernel<<<cdiv(E, 256), 256, 0, stream>>>(dst, deg, E);
  dinv_kernel<<<cdiv(n, 256), 256, 0, stream>>>(deg, dinv, n);
  scan1_kernel<<<nb, 256, 0, stream>>>(deg, offs, bsums, n);
  scan2_kernel<<<1, 256, 0, stream>>>(bsums, nb);
  scan3_kernel<<<cdiv(n, 256), 256, 0, stream>>>(offs, cursor, bsums, n, E);
  csr_kernel<<<cdiv(E, 256), 256, 0, stream>>>(src, dst, cursor, csrsrc, E);
  gemm_kernel<<<cdiv(n, BM), 256, 0, stream>>>(x, W, h, n);
  int tail = out_size - n * OUT_C;
  gather_kernel<<<cdiv(n, 4), 256, 0, stream>>>(offs, csrsrc, h, dinv, b, out, n, tail);
}

// Round 4
// 415.745 us; speedup vs baseline: 7.1122x; 1.1993x over previous
//
#include <hip/hip_runtime.h>

#define IN_C 512
#define OUT_C 128
#define SCAN_TILE 2048

typedef float f32x4 __attribute__((ext_vector_type(4)));
typedef __bf16 bf16x8 __attribute__((ext_vector_type(8)));

static inline int cdiv(int a, int b) { return (a + b - 1) / b; }

__device__ __forceinline__ int atomAddI(int* p, int v) {
  return __hip_atomic_fetch_add(p, v, __ATOMIC_RELAXED, __HIP_MEMORY_SCOPE_AGENT);
}
__device__ __forceinline__ unsigned short bfbits(__bf16 h) {
  return __builtin_bit_cast(unsigned short, h);
}

__global__ __launch_bounds__(256) void zero_i_kernel(int* __restrict__ p, int n) {
  int i = blockIdx.x * 256 + threadIdx.x;
  if (i < n) p[i] = 0;
}

__global__ __launch_bounds__(256) void deg_kernel(const int* __restrict__ dst,
                                                  int* __restrict__ deg, int E) {
  int e = blockIdx.x * 256 + threadIdx.x;
  if (e < E) atomAddI(&deg[dst[e]], 1);
}

__global__ __launch_bounds__(256) void dinv_kernel(const int* __restrict__ deg,
                                                   float* __restrict__ dinv, int n) {
  int i = blockIdx.x * 256 + threadIdx.x;
  if (i < n) dinv[i] = rsqrtf((float)deg[i] + 1.0f);
}

// ---- 3-phase exclusive scan of deg -> offs ----
__global__ __launch_bounds__(256) void scan1_kernel(const int* __restrict__ deg,
                                                    int* __restrict__ offs,
                                                    int* __restrict__ bsums, int n) {
  __shared__ int sh[256];
  int t = threadIdx.x;
  int base = blockIdx.x * SCAN_TILE + t * 8;
  int v[8];
  int s = 0;
#pragma unroll
  for (int i = 0; i < 8; i++) {
    int idx = base + i;
    v[i] = (idx < n) ? deg[idx] : 0;
    s += v[i];
  }
  sh[t] = s;
  __syncthreads();
  for (int off = 1; off < 256; off <<= 1) {
    int x = sh[t];
    if (t >= off) x += sh[t - off];
    __syncthreads();
    sh[t] = x;
    __syncthreads();
  }
  int run = sh[t] - s;
#pragma unroll
  for (int i = 0; i < 8; i++) {
    int idx = base + i;
    if (idx < n) offs[idx] = run;
    run += v[i];
  }
  if (t == 255) bsums[blockIdx.x] = sh[255];
}

__global__ __launch_bounds__(256) void scan2_kernel(int* __restrict__ bsums, int nb) {
  __shared__ int sh[256];
  int t = threadIdx.x;
  int v = (t < nb) ? bsums[t] : 0;
  sh[t] = v;
  __syncthreads();
  for (int off = 1; off < 256; off <<= 1) {
    int x = sh[t];
    if (t >= off) x += sh[t - off];
    __syncthreads();
    sh[t] = x;
    __syncthreads();
  }
  if (t < nb) bsums[t] = sh[t] - v;
}

__global__ __launch_bounds__(256) void scan3_kernel(int* __restrict__ offs,
                                                    int* __restrict__ cursor,
                                                    const int* __restrict__ bsums,
                                                    int n, int E) {
  int i = blockIdx.x * 256 + threadIdx.x;
  if (i < n) {
    int o = offs[i] + bsums[i >> 11];
    offs[i] = o;
    cursor[i] = o;
  }
  if (i == 0) offs[n] = E;
}

__global__ __launch_bounds__(256) void csr_kernel(const int* __restrict__ src,
                                                  const int* __restrict__ dst,
                                                  int* __restrict__ cursor,
                                                  int* __restrict__ csr_src, int E) {
  int e = blockIdx.x * 256 + threadIdx.x;
  if (e < E) {
    int pos = atomAddI(&cursor[dst[e]], 1);
    csr_src[pos] = src[e];
  }
}

// W[512][128] fp32 -> Wt_hi/Wt_lo [128][512] bf16 (transposed, 2-term split)
__global__ __launch_bounds__(256) void wsplit_kernel(const float* __restrict__ W,
                                                     unsigned short* __restrict__ wthi,
                                                     unsigned short* __restrict__ wtlo) {
  int i = blockIdx.x * 256 + threadIdx.x;  // 65536 total
  if (i >= IN_C * OUT_C) return;
  int k = i >> 7;
  int nn = i & 127;
  float w = W[i];
  __bf16 h = (__bf16)w;
  __bf16 l = (__bf16)(w - (float)h);
  wthi[(size_t)nn * IN_C + k] = bfbits(h);
  wtlo[(size_t)nn * IN_C + k] = bfbits(l);
}

// h[n][128](bf16) = x[n][512] @ W[512][128] via split-bf16 MFMA.
// Block: 256 thr = 4 waves; tile 64 rows x 128 cols; BK=64 (8 chunks).
// Wave w owns cols [w*32, w*32+32) over all 64 rows.
__global__ __launch_bounds__(256) void gemm_mfma_kernel(
    const float* __restrict__ x, const unsigned short* __restrict__ wthi,
    const unsigned short* __restrict__ wtlo, unsigned short* __restrict__ h, int n) {
  __shared__ unsigned short Ah[64][72];   // pad->row stride 144B: conflict-free b128
  __shared__ unsigned short Al[64][72];
  __shared__ unsigned short Bh[128][72];
  __shared__ unsigned short Bl[128][72];

  const int tid = threadIdx.x;
  const int w = tid >> 6;
  const int lane = tid & 63;
  const int l15 = lane & 15;
  const int lg = lane >> 4;  // 0..3
  const int row0 = blockIdx.x * 64;

  // A staging: thread -> (arow, 16 consecutive k); 256 thr x 16 = 64 rows x 64 k
  const int arow = tid >> 2;
  const int ak = (tid & 3) * 16;
  int gr = row0 + arow;
  if (gr > n - 1) gr = n - 1;
  const float* xp = x + (size_t)gr * IN_C + ak;
  // B staging: thread -> (brow, 32 consecutive k); 256 thr x 32 = 128 rows x 64 k
  const int brow = tid >> 1;
  const int bk = (tid & 1) * 32;
  const unsigned short* bhp = wthi + (size_t)brow * IN_C + bk;
  const unsigned short* blp = wtlo + (size_t)brow * IN_C + bk;

  f32x4 acc[4][2];
#pragma unroll
  for (int i = 0; i < 4; i++)
#pragma unroll
    for (int j = 0; j < 2; j++) acc[i][j] = (f32x4)0.0f;

  float4 xa[4];
  uint4 bhv[4], blv[4];
#pragma unroll
  for (int j = 0; j < 4; j++) xa[j] = *(const float4*)(xp + j * 4);
#pragma unroll
  for (int j = 0; j < 4; j++) {
    bhv[j] = *(const uint4*)(bhp + j * 8);
    blv[j] = *(const uint4*)(blp + j * 8);
  }

  for (int c = 0; c < 8; c++) {
    __syncthreads();
    // write A tile (convert fp32 -> hi/lo bf16)
#pragma unroll
    for (int j = 0; j < 4; j++) {
      float f[4] = {xa[j].x, xa[j].y, xa[j].z, xa[j].w};
      ushort4 hh, ll;
      unsigned short* hp_ = &hh.x;
      unsigned short* lp_ = &ll.x;
#pragma unroll
      for (int q = 0; q < 4; q++) {
        __bf16 hb = (__bf16)f[q];
        hp_[q] = bfbits(hb);
        lp_[q] = bfbits((__bf16)(f[q] - (float)hb));
      }
      *(ushort4*)&Ah[arow][ak + j * 4] = hh;
      *(ushort4*)&Al[arow][ak + j * 4] = ll;
    }
    // write B tile (4x uint4 = 32 shorts covering bk..bk+31)
#pragma unroll
    for (int j = 0; j < 4; j++) {
      *(uint4*)&Bh[brow][bk + j * 8] = bhv[j];
      *(uint4*)&Bl[brow][bk + j * 8] = blv[j];
    }
    // prefetch next chunk
    if (c < 7) {
      xp += 64;
      bhp += 64;
      blp += 64;
#pragma unroll
      for (int j = 0; j < 4; j++) xa[j] = *(const float4*)(xp + j * 4);
#pragma unroll
      for (int j = 0; j < 4; j++) {
        bhv[j] = *(const uint4*)(bhp + j * 8);
        blv[j] = *(const uint4*)(blp + j * 8);
      }
    }
    __syncthreads();
#pragma unroll
    for (int ks = 0; ks < 2; ks++) {
      const int ko = ks * 32 + lg * 8;
      bf16x8 ah[4], al[4], bh[2], bl[2];
#pragma unroll
      for (int rt = 0; rt < 4; rt++) {
        ah[rt] = *(const bf16x8*)&Ah[rt * 16 + l15][ko];
        al[rt] = *(const bf16x8*)&Al[rt * 16 + l15][ko];
      }
#pragma unroll
      for (int nt = 0; nt < 2; nt++) {
        bh[nt] = *(const bf16x8*)&Bh[w * 32 + nt * 16 + l15][ko];
        bl[nt] = *(const bf16x8*)&Bl[w * 32 + nt * 16 + l15][ko];
      }
#pragma unroll
      for (int rt = 0; rt < 4; rt++)
#pragma unroll
        for (int nt = 0; nt < 2; nt++) {
          acc[rt][nt] = __builtin_amdgcn_mfma_f32_16x16x32_bf16(ah[rt], bh[nt], acc[rt][nt], 0, 0, 0);
          acc[rt][nt] = __builtin_amdgcn_mfma_f32_16x16x32_bf16(ah[rt], bl[nt], acc[rt][nt], 0, 0, 0);
          acc[rt][nt] = __builtin_amdgcn_mfma_f32_16x16x32_bf16(al[rt], bh[nt], acc[rt][nt], 0, 0, 0);
        }
    }
  }

  // store h as bf16: D row=(lane>>4)*4+reg, col=lane&15 within each 16x16 tile
#pragma unroll
  for (int rt = 0; rt < 4; rt++) {
    int rowbase = row0 + rt * 16 + lg * 4;
#pragma unroll
    for (int nt = 0; nt < 2; nt++) {
      int col = w * 32 + nt * 16 + l15;
#pragma unroll
      for (int r = 0; r < 4; r++) {
        int row = rowbase + r;
        if (row < n) h[(size_t)row * OUT_C + col] = bfbits((__bf16)acc[rt][nt][r]);
      }
    }
  }
}

__device__ __forceinline__ float bflo(unsigned int u) {
  return __builtin_bit_cast(float, u << 16);
}
__device__ __forceinline__ float bfhi(unsigned int u) {
  return __builtin_bit_cast(float, u & 0xffff0000u);
}

// One wave per node: out[d] = dinv[d]*(sum_e h[src]*dinv[src] + h[d]*dinv[d]) + b
__global__ __launch_bounds__(256) void gather_kernel(const int* __restrict__ offs,
                                                     const int* __restrict__ csr_src,
                                                     const unsigned int* __restrict__ hp,
                                                     const float* __restrict__ dinv,
                                                     const float* __restrict__ b,
                                                     float* __restrict__ out,
                                                     int n, int tail) {
  int wid = threadIdx.x >> 6;
  int lane = threadIdx.x & 63;
  int node = blockIdx.x * 4 + wid;
  if (node >= n) return;

  int start = offs[node];
  int end = offs[node + 1];

  float accx = 0.0f, accy = 0.0f;
  int e = start;
  for (; e + 4 <= end; e += 4) {
    int s0 = csr_src[e + 0];
    int s1 = csr_src[e + 1];
    int s2 = csr_src[e + 2];
    int s3 = csr_src[e + 3];
    float w0 = dinv[s0], w1 = dinv[s1], w2 = dinv[s2], w3 = dinv[s3];
    unsigned int u0 = hp[(size_t)s0 * 64 + lane];
    unsigned int u1 = hp[(size_t)s1 * 64 + lane];
    unsigned int u2 = hp[(size_t)s2 * 64 + lane];
    unsigned int u3 = hp[(size_t)s3 * 64 + lane];
    accx += bflo(u0) * w0 + bflo(u1) * w1 + bflo(u2) * w2 + bflo(u3) * w3;
    accy += bfhi(u0) * w0 + bfhi(u1) * w1 + bfhi(u2) * w2 + bfhi(u3) * w3;
  }
  for (; e < end; e++) {
    int s = csr_src[e];
    float w = dinv[s];
    unsigned int u = hp[(size_t)s * 64 + lane];
    accx += bflo(u) * w;
    accy += bfhi(u) * w;
  }

  float dd = dinv[node];
  unsigned int us = hp[(size_t)node * 64 + lane];
  accx = (accx + bflo(us) * dd) * dd;
  accy = (accy + bfhi(us) * dd) * dd;
  float2 bb = ((const float2*)b)[lane];
  float2 o = make_float2(accx + bb.x, accy + bb.y);
  ((float2*)out)[(size_t)node * 64 + lane] = o;

  if (node == 0 && lane == 0) {
    for (int t = 0; t < tail; t++) out[(size_t)n * OUT_C + t] = 0.0f;
  }
}

extern "C" void kernel_launch(void* const* d_in, const int* in_sizes, int n_in,
                              void* d_out, int out_size, void* d_ws, size_t ws_size,
                              hipStream_t stream) {
  const float* x = (const float*)d_in[0];
  const int* ei = (const int*)d_in[1];
  const float* W = (const float*)d_in[2];
  const float* b = (const float*)d_in[3];

  const int n = in_sizes[0] / IN_C;
  const int E = in_sizes[1] / 2;
  const int* src = ei;
  const int* dst = ei + E;
  float* out = (float*)d_out;

  size_t p = 0;
  auto alloc = [&](size_t bytes) { size_t o = p; p += (bytes + 255) & ~(size_t)255; return o; };
  char* ws = (char*)d_ws;
  float*          dinv   = (float*)(ws + alloc((size_t)n * 4));
  unsigned short* h      = (unsigned short*)(ws + alloc((size_t)n * OUT_C * 2));
  int*            offs   = (int*)(ws + alloc(((size_t)n + 1) * 4));
  int*            csrsrc = (int*)(ws + alloc((size_t)E * 4));
  int*            deg    = (int*)(ws + alloc((size_t)n * 4));
  int*            bsums  = (int*)(ws + alloc(256 * 4));
  unsigned short* wthi   = (unsigned short*)(ws + alloc((size_t)IN_C * OUT_C * 2));
  unsigned short* wtlo   = (unsigned short*)(ws + alloc((size_t)IN_C * OUT_C * 2));
  int* cursor = deg;

  const int nb = cdiv(n, SCAN_TILE);

  wsplit_kernel<<<cdiv(IN_C * OUT_C, 256), 256, 0, stream>>>(W, wthi, wtlo);
  zero_i_kernel<<<cdiv(n, 256), 256, 0, stream>>>(deg, n);
  deg_kernel<<<cdiv(E, 256), 256, 0, stream>>>(dst, deg, E);
  dinv_kernel<<<cdiv(n, 256), 256, 0, stream>>>(deg, dinv, n);
  scan1_kernel<<<nb, 256, 0, stream>>>(deg, offs, bsums, n);
  scan2_kernel<<<1, 256, 0, stream>>>(bsums, nb);
  scan3_kernel<<<cdiv(n, 256), 256, 0, stream>>>(offs, cursor, bsums, n, E);
  csr_kernel<<<cdiv(E, 256), 256, 0, stream>>>(src, dst, cursor, csrsrc, E);
  gemm_mfma_kernel<<<cdiv(n, 64), 256, 0, stream>>>(x, wthi, wtlo, h, n);
  int tail = out_size - n * OUT_C;
  gather_kernel<<<cdiv(n, 4), 256, 0, stream>>>(offs, csrsrc, (const unsigned int*)h, dinv, b, out, n, tail);
}

// Round 5
// 379.291 us; speedup vs baseline: 7.7958x; 1.0961x over previous
//
#include <hip/hip_runtime.h>

#define IN_C 512
#define OUT_C 128
#define SCAN_TILE 2048

typedef float f32x4 __attribute__((ext_vector_type(4)));
typedef __bf16 bf16x8 __attribute__((ext_vector_type(8)));

static inline int cdiv(int a, int b) { return (a + b - 1) / b; }

__device__ __forceinline__ int atomAddI(int* p, int v) {
  return __hip_atomic_fetch_add(p, v, __ATOMIC_RELAXED, __HIP_MEMORY_SCOPE_AGENT);
}
__device__ __forceinline__ unsigned short bfbits(__bf16 h) {
  return __builtin_bit_cast(unsigned short, h);
}

__global__ __launch_bounds__(256) void zero_i_kernel(int* __restrict__ p, int n) {
  int i = blockIdx.x * 256 + threadIdx.x;
  if (i < n) p[i] = 0;
}

__global__ __launch_bounds__(256) void deg_kernel(const int* __restrict__ dst,
                                                  int* __restrict__ deg, int E) {
  int e = blockIdx.x * 256 + threadIdx.x;
  if (e < E) atomAddI(&deg[dst[e]], 1);
}

__global__ __launch_bounds__(256) void dinv_kernel(const int* __restrict__ deg,
                                                   float* __restrict__ dinv, int n) {
  int i = blockIdx.x * 256 + threadIdx.x;
  if (i < n) dinv[i] = rsqrtf((float)deg[i] + 1.0f);
}

// ---- 3-phase exclusive scan of deg -> offs ----
__global__ __launch_bounds__(256) void scan1_kernel(const int* __restrict__ deg,
                                                    int* __restrict__ offs,
                                                    int* __restrict__ bsums, int n) {
  __shared__ int sh[256];
  int t = threadIdx.x;
  int base = blockIdx.x * SCAN_TILE + t * 8;
  int v[8];
  int s = 0;
#pragma unroll
  for (int i = 0; i < 8; i++) {
    int idx = base + i;
    v[i] = (idx < n) ? deg[idx] : 0;
    s += v[i];
  }
  sh[t] = s;
  __syncthreads();
  for (int off = 1; off < 256; off <<= 1) {
    int x = sh[t];
    if (t >= off) x += sh[t - off];
    __syncthreads();
    sh[t] = x;
    __syncthreads();
  }
  int run = sh[t] - s;
#pragma unroll
  for (int i = 0; i < 8; i++) {
    int idx = base + i;
    if (idx < n) offs[idx] = run;
    run += v[i];
  }
  if (t == 255) bsums[blockIdx.x] = sh[255];
}

__global__ __launch_bounds__(256) void scan2_kernel(int* __restrict__ bsums, int nb) {
  __shared__ int sh[256];
  int t = threadIdx.x;
  int v = (t < nb) ? bsums[t] : 0;
  sh[t] = v;
  __syncthreads();
  for (int off = 1; off < 256; off <<= 1) {
    int x = sh[t];
    if (t >= off) x += sh[t - off];
    __syncthreads();
    sh[t] = x;
    __syncthreads();
  }
  if (t < nb) bsums[t] = sh[t] - v;
}

__global__ __launch_bounds__(256) void scan3_kernel(int* __restrict__ offs,
                                                    int* __restrict__ cursor,
                                                    const int* __restrict__ bsums,
                                                    int n, int E) {
  int i = blockIdx.x * 256 + threadIdx.x;
  if (i < n) {
    int o = offs[i] + bsums[i >> 11];
    offs[i] = o;
    cursor[i] = o;
  }
  if (i == 0) offs[n] = E;
}

__global__ __launch_bounds__(256) void csr_kernel(const int* __restrict__ src,
                                                  const int* __restrict__ dst,
                                                  int* __restrict__ cursor,
                                                  int* __restrict__ csr_src, int E) {
  int e = blockIdx.x * 256 + threadIdx.x;
  if (e < E) {
    int pos = atomAddI(&cursor[dst[e]], 1);
    csr_src[pos] = src[e];
  }
}

// W[512][128] fp32 -> fragment-major bf16 hi/lo for direct MFMA B-operand loads.
// frag idx for (k, col): ks=k>>5, lg=(k&31)>>3, j=k&7, cb=col>>4, l15=col&15,
// lane=lg*16+l15, out[((ks*8+cb)*64+lane)*8+j]
__global__ __launch_bounds__(256) void wsplit_kernel(const float* __restrict__ W,
                                                     unsigned short* __restrict__ wfh,
                                                     unsigned short* __restrict__ wfl) {
  int i = blockIdx.x * 256 + threadIdx.x;  // 65536 total
  if (i >= IN_C * OUT_C) return;
  int k = i >> 7;
  int col = i & 127;
  float w = W[i];
  __bf16 hb = (__bf16)w;
  __bf16 lb = (__bf16)(w - (float)hb);
  int ks = k >> 5;
  int lg = (k & 31) >> 3;
  int j = k & 7;
  int cb = col >> 4;
  int lane = lg * 16 + (col & 15);
  size_t idx = ((size_t)(ks * 8 + cb) * 64 + lane) * 8 + j;
  wfh[idx] = bfbits(hb);
  wfl[idx] = bfbits(lb);
}

// h[n][128](bf16) = x @ W via split-bf16 MFMA, zero-LDS.
// Block: 256 thr = 4 waves (2x2); wave tile 64 rows x 64 cols (rt=4, nt=4).
// A frags loaded directly from x (lane = row l15, k = lg*8..+7), hi/lo split in regs.
// B frags loaded directly from fragment-major wfh/wfl (L2-resident).
__global__ __launch_bounds__(256) void gemm_mfma_kernel(
    const float* __restrict__ x, const unsigned short* __restrict__ wfh,
    const unsigned short* __restrict__ wfl, unsigned short* __restrict__ h, int n) {
  const int tid = threadIdx.x;
  const int wv = tid >> 6;
  const int lane = tid & 63;
  const int l15 = lane & 15;
  const int lg = lane >> 4;
  const int wr = wv >> 1;
  const int wc = wv & 1;
  const int rowW = blockIdx.x * 128 + wr * 64;
  const int colW = wc * 64;

  const float* ap[4];
#pragma unroll
  for (int rt = 0; rt < 4; rt++) {
    int r = rowW + rt * 16 + l15;
    if (r > n - 1) r = n - 1;
    ap[rt] = x + (size_t)r * IN_C + lg * 8;
  }
  const unsigned short* bph = wfh + ((size_t)(wc * 4) * 64 + lane) * 8;
  const unsigned short* bpl = wfl + ((size_t)(wc * 4) * 64 + lane) * 8;

  f32x4 acc[4][4];
#pragma unroll
  for (int i = 0; i < 4; i++)
#pragma unroll
    for (int j = 0; j < 4; j++) acc[i][j] = (f32x4)0.0f;

#pragma unroll 2
  for (int ks = 0; ks < 16; ks++) {
    bf16x8 bh[4], bl[4];
#pragma unroll
    for (int nt = 0; nt < 4; nt++) {
      bh[nt] = __builtin_bit_cast(bf16x8, *(const uint4*)(bph + ks * 4096 + nt * 512));
      bl[nt] = __builtin_bit_cast(bf16x8, *(const uint4*)(bpl + ks * 4096 + nt * 512));
    }
    bf16x8 ah[4], al[4];
#pragma unroll
    for (int rt = 0; rt < 4; rt++) {
      float4 f0 = *(const float4*)(ap[rt] + ks * 32);
      float4 f1 = *(const float4*)(ap[rt] + ks * 32 + 4);
      float f[8] = {f0.x, f0.y, f0.z, f0.w, f1.x, f1.y, f1.z, f1.w};
      bf16x8 hh, ll;
#pragma unroll
      for (int j = 0; j < 8; j++) {
        __bf16 hb = (__bf16)f[j];
        hh[j] = hb;
        ll[j] = (__bf16)(f[j] - (float)hb);
      }
      ah[rt] = hh;
      al[rt] = ll;
    }
#pragma unroll
    for (int rt = 0; rt < 4; rt++)
#pragma unroll
      for (int nt = 0; nt < 4; nt++) {
        acc[rt][nt] = __builtin_amdgcn_mfma_f32_16x16x32_bf16(ah[rt], bh[nt], acc[rt][nt], 0, 0, 0);
        acc[rt][nt] = __builtin_amdgcn_mfma_f32_16x16x32_bf16(ah[rt], bl[nt], acc[rt][nt], 0, 0, 0);
        acc[rt][nt] = __builtin_amdgcn_mfma_f32_16x16x32_bf16(al[rt], bh[nt], acc[rt][nt], 0, 0, 0);
      }
  }

  // store h bf16: D row=(lane>>4)*4+reg, col=lane&15 per 16x16 tile
#pragma unroll
  for (int rt = 0; rt < 4; rt++) {
    int rowbase = rowW + rt * 16 + lg * 4;
#pragma unroll
    for (int nt = 0; nt < 4; nt++) {
      int col = colW + nt * 16 + l15;
#pragma unroll
      for (int r = 0; r < 4; r++) {
        int row = rowbase + r;
        if (row < n) h[(size_t)row * OUT_C + col] = bfbits((__bf16)acc[rt][nt][r]);
      }
    }
  }
}

__device__ __forceinline__ float bflo(unsigned int u) {
  return __builtin_bit_cast(float, u << 16);
}
__device__ __forceinline__ float bfhi(unsigned int u) {
  return __builtin_bit_cast(float, u & 0xffff0000u);
}

// One wave per node: out[d] = dinv[d]*(sum_e h[src]*dinv[src] + h[d]*dinv[d]) + b
__global__ __launch_bounds__(256) void gather_kernel(const int* __restrict__ offs,
                                                     const int* __restrict__ csr_src,
                                                     const unsigned int* __restrict__ hp,
                                                     const float* __restrict__ dinv,
                                                     const float* __restrict__ b,
                                                     float* __restrict__ out,
                                                     int n, int tail) {
  int wid = threadIdx.x >> 6;
  int lane = threadIdx.x & 63;
  int node = blockIdx.x * 4 + wid;
  if (node >= n) return;

  int start = offs[node];
  int end = offs[node + 1];

  float accx = 0.0f, accy = 0.0f;
  int e = start;
  for (; e + 4 <= end; e += 4) {
    int s0 = csr_src[e + 0];
    int s1 = csr_src[e + 1];
    int s2 = csr_src[e + 2];
    int s3 = csr_src[e + 3];
    float w0 = dinv[s0], w1 = dinv[s1], w2 = dinv[s2], w3 = dinv[s3];
    unsigned int u0 = hp[(size_t)s0 * 64 + lane];
    unsigned int u1 = hp[(size_t)s1 * 64 + lane];
    unsigned int u2 = hp[(size_t)s2 * 64 + lane];
    unsigned int u3 = hp[(size_t)s3 * 64 + lane];
    accx += bflo(u0) * w0 + bflo(u1) * w1 + bflo(u2) * w2 + bflo(u3) * w3;
    accy += bfhi(u0) * w0 + bfhi(u1) * w1 + bfhi(u2) * w2 + bfhi(u3) * w3;
  }
  for (; e < end; e++) {
    int s = csr_src[e];
    float w = dinv[s];
    unsigned int u = hp[(size_t)s * 64 + lane];
    accx += bflo(u) * w;
    accy += bfhi(u) * w;
  }

  float dd = dinv[node];
  unsigned int us = hp[(size_t)node * 64 + lane];
  accx = (accx + bflo(us) * dd) * dd;
  accy = (accy + bfhi(us) * dd) * dd;
  float2 bb = ((const float2*)b)[lane];
  float2 o = make_float2(accx + bb.x, accy + bb.y);
  ((float2*)out)[(size_t)node * 64 + lane] = o;

  if (node == 0 && lane == 0) {
    for (int t = 0; t < tail; t++) out[(size_t)n * OUT_C + t] = 0.0f;
  }
}

extern "C" void kernel_launch(void* const* d_in, const int* in_sizes, int n_in,
                              void* d_out, int out_size, void* d_ws, size_t ws_size,
                              hipStream_t stream) {
  const float* x = (const float*)d_in[0];
  const int* ei = (const int*)d_in[1];
  const float* W = (const float*)d_in[2];
  const float* b = (const float*)d_in[3];

  const int n = in_sizes[0] / IN_C;
  const int E = in_sizes[1] / 2;
  const int* src = ei;
  const int* dst = ei + E;
  float* out = (float*)d_out;

  size_t p = 0;
  auto alloc = [&](size_t bytes) { size_t o = p; p += (bytes + 255) & ~(size_t)255; return o; };
  char* ws = (char*)d_ws;
  float*          dinv   = (float*)(ws + alloc((size_t)n * 4));
  unsigned short* h      = (unsigned short*)(ws + alloc((size_t)n * OUT_C * 2));
  int*            offs   = (int*)(ws + alloc(((size_t)n + 1) * 4));
  int*            csrsrc = (int*)(ws + alloc((size_t)E * 4));
  int*            deg    = (int*)(ws + alloc((size_t)n * 4));
  int*            bsums  = (int*)(ws + alloc(256 * 4));
  unsigned short* wfh    = (unsigned short*)(ws + alloc((size_t)IN_C * OUT_C * 2));
  unsigned short* wfl    = (unsigned short*)(ws + alloc((size_t)IN_C * OUT_C * 2));
  int* cursor = deg;

  const int nb = cdiv(n, SCAN_TILE);

  wsplit_kernel<<<cdiv(IN_C * OUT_C, 256), 256, 0, stream>>>(W, wfh, wfl);
  zero_i_kernel<<<cdiv(n, 256), 256, 0, stream>>>(deg, n);
  deg_kernel<<<cdiv(E, 256), 256, 0, stream>>>(dst, deg, E);
  dinv_kernel<<<cdiv(n, 256), 256, 0, stream>>>(deg, dinv, n);
  scan1_kernel<<<nb, 256, 0, stream>>>(deg, offs, bsums, n);
  scan2_kernel<<<1, 256, 0, stream>>>(bsums, nb);
  scan3_kernel<<<cdiv(n, 256), 256, 0, stream>>>(offs, cursor, bsums, n, E);
  csr_kernel<<<cdiv(E, 256), 256, 0, stream>>>(src, dst, cursor, csrsrc, E);
  gemm_mfma_kernel<<<cdiv(n, 128), 256, 0, stream>>>(x, wfh, wfl, h, n);
  int tail = out_size - n * OUT_C;
  gather_kernel<<<cdiv(n, 4), 256, 0, stream>>>(offs, csrsrc, (const unsigned int*)h, dinv, b, out, n, tail);
}

// Round 6
// 348.849 us; speedup vs baseline: 8.4761x; 1.0873x over previous
//
#include <hip/hip_runtime.h>

#define IN_C 512
#define OUT_C 128
#define SCAN_TILE 2048
#define NB 128          // dst buckets (dst >> 10)
#define CHUNK 8192      // edges per histogram/scatter chunk

typedef float f32x4 __attribute__((ext_vector_type(4)));
typedef __bf16 bf16x8 __attribute__((ext_vector_type(8)));

static inline int cdiv(int a, int b) { return (a + b - 1) / b; }

__device__ __forceinline__ unsigned short bfbits(__bf16 h) {
  return __builtin_bit_cast(unsigned short, h);
}

// ---- CSR build: two-level counting sort (no global atomics) ----

// per-chunk histogram of dst buckets -> table[bucket][chunk]
__global__ __launch_bounds__(256) void hist_kernel(const int* __restrict__ dst,
                                                   int* __restrict__ table,
                                                   int nchunks, int E) {
  __shared__ int hcnt[NB];
  int t = threadIdx.x;
  int c = blockIdx.x;
  if (t < NB) hcnt[t] = 0;
  __syncthreads();
  int base = c * CHUNK;
  for (int i = t; i < CHUNK; i += 256) {
    int e = base + i;
    if (e < E) atomicAdd(&hcnt[dst[e] >> 10], 1);
  }
  __syncthreads();
  if (t < NB) table[t * nchunks + c] = hcnt[t];
}

// single-WG exclusive scan of table (bucket-major); emits bucket starts
__global__ __launch_bounds__(256) void tscan_kernel(int* __restrict__ table,
                                                    int* __restrict__ bstart,
                                                    int nchunks, int E) {
  __shared__ int sh[256];
  int t = threadIdx.x;
  int total = NB * nchunks;
  int S = (total + 255) / 256;
  int lo = t * S;
  int hi = lo + S; if (hi > total) hi = total;
  int s = 0;
  int i = lo;
  for (; i + 4 <= hi; i += 4)
    s += table[i] + table[i + 1] + table[i + 2] + table[i + 3];
  for (; i < hi; i++) s += table[i];
  sh[t] = s;
  __syncthreads();
  for (int off = 1; off < 256; off <<= 1) {
    int x = sh[t];
    if (t >= off) x += sh[t - off];
    __syncthreads();
    sh[t] = x;
    __syncthreads();
  }
  int run = sh[t] - s;
  for (i = lo; i < hi; i++) {
    int v = table[i];
    table[i] = run;
    run += v;
  }
  __syncthreads();
  for (int b = t; b < NB; b += 256) bstart[b] = table[b * nchunks];
  if (t == 0) bstart[NB] = E;
}

// scatter edges into bucket-major inter[] (private (chunk,bucket) regions)
__global__ __launch_bounds__(256) void scat2_kernel(const int* __restrict__ src,
                                                    const int* __restrict__ dst,
                                                    const int* __restrict__ table,
                                                    int2* __restrict__ inter,
                                                    int nchunks, int E) {
  __shared__ int cur[NB];
  int t = threadIdx.x;
  int c = blockIdx.x;
  if (t < NB) cur[t] = table[t * nchunks + c];
  __syncthreads();
  int base = c * CHUNK;
  for (int i = t; i < CHUNK; i += 256) {
    int e = base + i;
    if (e < E) {
      int d = dst[e];
      int pos = atomicAdd(&cur[d >> 10], 1);
      inter[pos] = make_int2(src[e], d);
    }
  }
}

// per-bucket degree count (LDS atomics) -> deg[]
__global__ __launch_bounds__(256) void bdeg_kernel(const int2* __restrict__ inter,
                                                   const int* __restrict__ bstart,
                                                   int* __restrict__ deg, int n) {
  __shared__ int dl[1024];
  int t = threadIdx.x;
  int b = blockIdx.x;
  for (int i = t; i < 1024; i += 256) dl[i] = 0;
  __syncthreads();
  int lo = bstart[b], hi = bstart[b + 1];
  for (int e = lo + t; e < hi; e += 256) atomicAdd(&dl[inter[e].y & 1023], 1);
  __syncthreads();
  int nb0 = b << 10;
  for (int i = t; i < 1024; i += 256) {
    int node = nb0 + i;
    if (node < n) deg[node] = dl[i];
  }
}

__global__ __launch_bounds__(256) void dinv_kernel(const int* __restrict__ deg,
                                                   float* __restrict__ dinv, int n) {
  int i = blockIdx.x * 256 + threadIdx.x;
  if (i < n) dinv[i] = rsqrtf((float)deg[i] + 1.0f);
}

// ---- 3-phase exclusive scan of deg -> offs ----
__global__ __launch_bounds__(256) void scan1_kernel(const int* __restrict__ deg,
                                                    int* __restrict__ offs,
                                                    int* __restrict__ bsums, int n) {
  __shared__ int sh[256];
  int t = threadIdx.x;
  int base = blockIdx.x * SCAN_TILE + t * 8;
  int v[8];
  int s = 0;
#pragma unroll
  for (int i = 0; i < 8; i++) {
    int idx = base + i;
    v[i] = (idx < n) ? deg[idx] : 0;
    s += v[i];
  }
  sh[t] = s;
  __syncthreads();
  for (int off = 1; off < 256; off <<= 1) {
    int x = sh[t];
    if (t >= off) x += sh[t - off];
    __syncthreads();
    sh[t] = x;
    __syncthreads();
  }
  int run = sh[t] - s;
#pragma unroll
  for (int i = 0; i < 8; i++) {
    int idx = base + i;
    if (idx < n) offs[idx] = run;
    run += v[i];
  }
  if (t == 255) bsums[blockIdx.x] = sh[255];
}

__global__ __launch_bounds__(256) void scan2_kernel(int* __restrict__ bsums, int nb) {
  __shared__ int sh[256];
  int t = threadIdx.x;
  int v = (t < nb) ? bsums[t] : 0;
  sh[t] = v;
  __syncthreads();
  for (int off = 1; off < 256; off <<= 1) {
    int x = sh[t];
    if (t >= off) x += sh[t - off];
    __syncthreads();
    sh[t] = x;
    __syncthreads();
  }
  if (t < nb) bsums[t] = sh[t] - v;
}

__global__ __launch_bounds__(256) void scan3_kernel(int* __restrict__ offs,
                                                    const int* __restrict__ bsums,
                                                    int n, int E) {
  int i = blockIdx.x * 256 + threadIdx.x;
  if (i < n) offs[i] = offs[i] + bsums[i >> 11];
  if (i == 0) offs[n] = E;
}

// per-bucket CSR fill via LDS cursors; writes stay in one XCD's L2
__global__ __launch_bounds__(256) void scat3_kernel(const int2* __restrict__ inter,
                                                    const int* __restrict__ bstart,
                                                    const int* __restrict__ offs,
                                                    int* __restrict__ csr_src, int n) {
  __shared__ int cur[1024];
  int t = threadIdx.x;
  int b = blockIdx.x;
  int nb0 = b << 10;
  for (int i = t; i < 1024; i += 256) {
    int node = nb0 + i;
    cur[i] = (node < n) ? offs[node] : 0;
  }
  __syncthreads();
  int lo = bstart[b], hi = bstart[b + 1];
  for (int e = lo + t; e < hi; e += 256) {
    int2 sd = inter[e];
    int pos = atomicAdd(&cur[sd.y & 1023], 1);
    csr_src[pos] = sd.x;
  }
}

// W[512][128] fp32 -> fragment-major bf16 hi/lo for direct MFMA B-operand loads.
__global__ __launch_bounds__(256) void wsplit_kernel(const float* __restrict__ W,
                                                     unsigned short* __restrict__ wfh,
                                                     unsigned short* __restrict__ wfl) {
  int i = blockIdx.x * 256 + threadIdx.x;  // 65536 total
  if (i >= IN_C * OUT_C) return;
  int k = i >> 7;
  int col = i & 127;
  float w = W[i];
  __bf16 hb = (__bf16)w;
  __bf16 lb = (__bf16)(w - (float)hb);
  int ks = k >> 5;
  int lg = (k & 31) >> 3;
  int j = k & 7;
  int cb = col >> 4;
  int lane = lg * 16 + (col & 15);
  size_t idx = ((size_t)(ks * 8 + cb) * 64 + lane) * 8 + j;
  wfh[idx] = bfbits(hb);
  wfl[idx] = bfbits(lb);
}

// h = x @ W via split-bf16 MFMA, zero-LDS.
// Block: 4 waves; tile 64 rows x 128 cols; wave wv owns cols [wv*32, wv*32+32).
__global__ __launch_bounds__(256) void gemm_mfma_kernel(
    const float* __restrict__ x, const unsigned short* __restrict__ wfh,
    const unsigned short* __restrict__ wfl, unsigned short* __restrict__ h, int n) {
  const int tid = threadIdx.x;
  const int wv = tid >> 6;
  const int lane = tid & 63;
  const int l15 = lane & 15;
  const int lg = lane >> 4;
  const int rowW = blockIdx.x * 64;

  const float* ap[4];
#pragma unroll
  for (int rt = 0; rt < 4; rt++) {
    int r = rowW + rt * 16 + l15;
    if (r > n - 1) r = n - 1;
    ap[rt] = x + (size_t)r * IN_C + lg * 8;
  }
  const unsigned short* bph = wfh + ((size_t)(wv * 2) * 64 + lane) * 8;
  const unsigned short* bpl = wfl + ((size_t)(wv * 2) * 64 + lane) * 8;

  f32x4 acc[4][2];
#pragma unroll
  for (int i = 0; i < 4; i++)
#pragma unroll
    for (int j = 0; j < 2; j++) acc[i][j] = (f32x4)0.0f;

#pragma unroll 2
  for (int ks = 0; ks < 16; ks++) {
    bf16x8 bh[2], bl[2];
#pragma unroll
    for (int nt = 0; nt < 2; nt++) {
      bh[nt] = __builtin_bit_cast(bf16x8, *(const uint4*)(bph + ks * 4096 + nt * 512));
      bl[nt] = __builtin_bit_cast(bf16x8, *(const uint4*)(bpl + ks * 4096 + nt * 512));
    }
    bf16x8 ah[4], al[4];
#pragma unroll
    for (int rt = 0; rt < 4; rt++) {
      float4 f0 = *(const float4*)(ap[rt] + ks * 32);
      float4 f1 = *(const float4*)(ap[rt] + ks * 32 + 4);
      float f[8] = {f0.x, f0.y, f0.z, f0.w, f1.x, f1.y, f1.z, f1.w};
      bf16x8 hh, ll;
#pragma unroll
      for (int j = 0; j < 8; j++) {
        __bf16 hb = (__bf16)f[j];
        hh[j] = hb;
        ll[j] = (__bf16)(f[j] - (float)hb);
      }
      ah[rt] = hh;
      al[rt] = ll;
    }
#pragma unroll
    for (int rt = 0; rt < 4; rt++)
#pragma unroll
      for (int nt = 0; nt < 2; nt++) {
        acc[rt][nt] = __builtin_amdgcn_mfma_f32_16x16x32_bf16(ah[rt], bh[nt], acc[rt][nt], 0, 0, 0);
        acc[rt][nt] = __builtin_amdgcn_mfma_f32_16x16x32_bf16(ah[rt], bl[nt], acc[rt][nt], 0, 0, 0);
        acc[rt][nt] = __builtin_amdgcn_mfma_f32_16x16x32_bf16(al[rt], bh[nt], acc[rt][nt], 0, 0, 0);
      }
  }

#pragma unroll
  for (int rt = 0; rt < 4; rt++) {
    int rowbase = rowW + rt * 16 + lg * 4;
#pragma unroll
    for (int nt = 0; nt < 2; nt++) {
      int col = (wv * 2 + nt) * 16 + l15;
#pragma unroll
      for (int r = 0; r < 4; r++) {
        int row = rowbase + r;
        if (row < n) h[(size_t)row * OUT_C + col] = bfbits((__bf16)acc[rt][nt][r]);
      }
    }
  }
}

__device__ __forceinline__ float bflo(unsigned int u) {
  return __builtin_bit_cast(float, u << 16);
}
__device__ __forceinline__ float bfhi(unsigned int u) {
  return __builtin_bit_cast(float, u & 0xffff0000u);
}

// One wave per node: out[d] = dinv[d]*(sum_e h[src]*dinv[src] + h[d]*dinv[d]) + b
__global__ __launch_bounds__(256) void gather_kernel(const int* __restrict__ offs,
                                                     const int* __restrict__ csr_src,
                                                     const unsigned int* __restrict__ hp,
                                                     const float* __restrict__ dinv,
                                                     const float* __restrict__ b,
                                                     float* __restrict__ out,
                                                     int n, int tail) {
  int wid = threadIdx.x >> 6;
  int lane = threadIdx.x & 63;
  int node = blockIdx.x * 4 + wid;
  if (node >= n) return;

  int start = offs[node];
  int end = offs[node + 1];

  float accx = 0.0f, accy = 0.0f;
  int e = start;
  for (; e + 4 <= end; e += 4) {
    int s0 = csr_src[e + 0];
    int s1 = csr_src[e + 1];
    int s2 = csr_src[e + 2];
    int s3 = csr_src[e + 3];
    float w0 = dinv[s0], w1 = dinv[s1], w2 = dinv[s2], w3 = dinv[s3];
    unsigned int u0 = hp[(size_t)s0 * 64 + lane];
    unsigned int u1 = hp[(size_t)s1 * 64 + lane];
    unsigned int u2 = hp[(size_t)s2 * 64 + lane];
    unsigned int u3 = hp[(size_t)s3 * 64 + lane];
    accx += bflo(u0) * w0 + bflo(u1) * w1 + bflo(u2) * w2 + bflo(u3) * w3;
    accy += bfhi(u0) * w0 + bfhi(u1) * w1 + bfhi(u2) * w2 + bfhi(u3) * w3;
  }
  for (; e < end; e++) {
    int s = csr_src[e];
    float w = dinv[s];
    unsigned int u = hp[(size_t)s * 64 + lane];
    accx += bflo(u) * w;
    accy += bfhi(u) * w;
  }

  float dd = dinv[node];
  unsigned int us = hp[(size_t)node * 64 + lane];
  accx = (accx + bflo(us) * dd) * dd;
  accy = (accy + bfhi(us) * dd) * dd;
  float2 bb = ((const float2*)b)[lane];
  float2 o = make_float2(accx + bb.x, accy + bb.y);
  ((float2*)out)[(size_t)node * 64 + lane] = o;

  if (node == 0 && lane == 0) {
    for (int t = 0; t < tail; t++) out[(size_t)n * OUT_C + t] = 0.0f;
  }
}

extern "C" void kernel_launch(void* const* d_in, const int* in_sizes, int n_in,
                              void* d_out, int out_size, void* d_ws, size_t ws_size,
                              hipStream_t stream) {
  const float* x = (const float*)d_in[0];
  const int* ei = (const int*)d_in[1];
  const float* W = (const float*)d_in[2];
  const float* b = (const float*)d_in[3];

  const int n = in_sizes[0] / IN_C;
  const int E = in_sizes[1] / 2;
  const int* src = ei;
  const int* dst = ei + E;
  float* out = (float*)d_out;

  const int nchunks = cdiv(E, CHUNK);
  const int nbk = cdiv(n, 1024);  // bucket workgroups

  size_t p = 0;
  auto alloc = [&](size_t bytes) { size_t o = p; p += (bytes + 255) & ~(size_t)255; return o; };
  char* ws = (char*)d_ws;
  float*          dinv   = (float*)(ws + alloc((size_t)n * 4));
  int*            offs   = (int*)(ws + alloc(((size_t)n + 1) * 4));
  int*            csrsrc = (int*)(ws + alloc((size_t)E * 4));
  int*            deg    = (int*)(ws + alloc((size_t)n * 4));
  int*            bsums  = (int*)(ws + alloc(256 * 4));
  int*            bstart = (int*)(ws + alloc((NB + 1) * 4));
  unsigned short* wfh    = (unsigned short*)(ws + alloc((size_t)IN_C * OUT_C * 2));
  unsigned short* wfl    = (unsigned short*)(ws + alloc((size_t)IN_C * OUT_C * 2));
  // union region: {inter + table} (CSR build) then reused as h (GEMM onward)
  size_t upos = p;
  int2*           inter  = (int2*)(ws + upos);
  int*            table  = (int*)(ws + upos + (((size_t)E * 8 + 255) & ~(size_t)255));
  unsigned short* h      = (unsigned short*)(ws + upos);

  const int nb = cdiv(n, SCAN_TILE);

  wsplit_kernel<<<cdiv(IN_C * OUT_C, 256), 256, 0, stream>>>(W, wfh, wfl);
  hist_kernel<<<nchunks, 256, 0, stream>>>(dst, table, nchunks, E);
  tscan_kernel<<<1, 256, 0, stream>>>(table, bstart, nchunks, E);
  scat2_kernel<<<nchunks, 256, 0, stream>>>(src, dst, table, inter, nchunks, E);
  bdeg_kernel<<<nbk, 256, 0, stream>>>(inter, bstart, deg, n);
  dinv_kernel<<<cdiv(n, 256), 256, 0, stream>>>(deg, dinv, n);
  scan1_kernel<<<nb, 256, 0, stream>>>(deg, offs, bsums, n);
  scan2_kernel<<<1, 256, 0, stream>>>(bsums, nb);
  scan3_kernel<<<cdiv(n, 256), 256, 0, stream>>>(offs, bsums, n, E);
  scat3_kernel<<<nbk, 256, 0, stream>>>(inter, bstart, offs, csrsrc, n);
  gemm_mfma_kernel<<<cdiv(n, 64), 256, 0, stream>>>(x, wfh, wfl, h, n);
  int tail = out_size - n * OUT_C;
  gather_kernel<<<cdiv(n, 4), 256, 0, stream>>>(offs, csrsrc, (const unsigned int*)h, dinv, b, out, n, tail);
}

// Round 7
// 288.105 us; speedup vs baseline: 10.2631x; 1.2108x over previous
//
#include <hip/hip_runtime.h>

#define IN_C 512
#define OUT_C 128
#define SCAN_TILE 2048
#define NB 128          // dst buckets (dst >> 10)
#define CHUNK 8192      // edges per histogram/scatter chunk

typedef float f32x4 __attribute__((ext_vector_type(4)));
typedef __bf16 bf16x8 __attribute__((ext_vector_type(8)));

static inline int cdiv(int a, int b) { return (a + b - 1) / b; }

__device__ __forceinline__ unsigned short bfbits(__bf16 h) {
  return __builtin_bit_cast(unsigned short, h);
}

// ---- CSR build: two-level counting sort (no global atomics) ----

__global__ __launch_bounds__(256) void hist_kernel(const int* __restrict__ dst,
                                                   int* __restrict__ table,
                                                   int nchunks, int E) {
  __shared__ int hcnt[NB];
  int t = threadIdx.x;
  int c = blockIdx.x;
  if (t < NB) hcnt[t] = 0;
  __syncthreads();
  int base = c * CHUNK;
  for (int i = t; i < CHUNK; i += 256) {
    int e = base + i;
    if (e < E) atomicAdd(&hcnt[dst[e] >> 10], 1);
  }
  __syncthreads();
  if (t < NB) table[t * nchunks + c] = hcnt[t];
}

__global__ __launch_bounds__(256) void tscan_kernel(int* __restrict__ table,
                                                    int* __restrict__ bstart,
                                                    int nchunks, int E) {
  __shared__ int sh[256];
  int t = threadIdx.x;
  int total = NB * nchunks;
  int S = (total + 255) / 256;
  int lo = t * S;
  int hi = lo + S; if (hi > total) hi = total;
  int s = 0;
  int i = lo;
  for (; i + 4 <= hi; i += 4)
    s += table[i] + table[i + 1] + table[i + 2] + table[i + 3];
  for (; i < hi; i++) s += table[i];
  sh[t] = s;
  __syncthreads();
  for (int off = 1; off < 256; off <<= 1) {
    int x = sh[t];
    if (t >= off) x += sh[t - off];
    __syncthreads();
    sh[t] = x;
    __syncthreads();
  }
  int run = sh[t] - s;
  for (i = lo; i < hi; i++) {
    int v = table[i];
    table[i] = run;
    run += v;
  }
  __syncthreads();
  for (int b = t; b < NB; b += 256) bstart[b] = table[b * nchunks];
  if (t == 0) bstart[NB] = E;
}

__global__ __launch_bounds__(256) void scat2_kernel(const int* __restrict__ src,
                                                    const int* __restrict__ dst,
                                                    const int* __restrict__ table,
                                                    int2* __restrict__ inter,
                                                    int nchunks, int E) {
  __shared__ int cur[NB];
  int t = threadIdx.x;
  int c = blockIdx.x;
  if (t < NB) cur[t] = table[t * nchunks + c];
  __syncthreads();
  int base = c * CHUNK;
  for (int i = t; i < CHUNK; i += 256) {
    int e = base + i;
    if (e < E) {
      int d = dst[e];
      int pos = atomicAdd(&cur[d >> 10], 1);
      inter[pos] = make_int2(src[e], d);
    }
  }
}

__global__ __launch_bounds__(256) void bdeg_kernel(const int2* __restrict__ inter,
                                                   const int* __restrict__ bstart,
                                                   int* __restrict__ deg, int n) {
  __shared__ int dl[1024];
  int t = threadIdx.x;
  int b = blockIdx.x;
  for (int i = t; i < 1024; i += 256) dl[i] = 0;
  __syncthreads();
  int lo = bstart[b], hi = bstart[b + 1];
  for (int e = lo + t; e < hi; e += 256) atomicAdd(&dl[inter[e].y & 1023], 1);
  __syncthreads();
  int nb0 = b << 10;
  for (int i = t; i < 1024; i += 256) {
    int node = nb0 + i;
    if (node < n) deg[node] = dl[i];
  }
}

__global__ __launch_bounds__(256) void dinv_kernel(const int* __restrict__ deg,
                                                   float* __restrict__ dinv, int n) {
  int i = blockIdx.x * 256 + threadIdx.x;
  if (i < n) dinv[i] = rsqrtf((float)deg[i] + 1.0f);
}

// ---- 3-phase exclusive scan of deg -> offs ----
__global__ __launch_bounds__(256) void scan1_kernel(const int* __restrict__ deg,
                                                    int* __restrict__ offs,
                                                    int* __restrict__ bsums, int n) {
  __shared__ int sh[256];
  int t = threadIdx.x;
  int base = blockIdx.x * SCAN_TILE + t * 8;
  int v[8];
  int s = 0;
#pragma unroll
  for (int i = 0; i < 8; i++) {
    int idx = base + i;
    v[i] = (idx < n) ? deg[idx] : 0;
    s += v[i];
  }
  sh[t] = s;
  __syncthreads();
  for (int off = 1; off < 256; off <<= 1) {
    int x = sh[t];
    if (t >= off) x += sh[t - off];
    __syncthreads();
    sh[t] = x;
    __syncthreads();
  }
  int run = sh[t] - s;
#pragma unroll
  for (int i = 0; i < 8; i++) {
    int idx = base + i;
    if (idx < n) offs[idx] = run;
    run += v[i];
  }
  if (t == 255) bsums[blockIdx.x] = sh[255];
}

__global__ __launch_bounds__(256) void scan2_kernel(int* __restrict__ bsums, int nb) {
  __shared__ int sh[256];
  int t = threadIdx.x;
  int v = (t < nb) ? bsums[t] : 0;
  sh[t] = v;
  __syncthreads();
  for (int off = 1; off < 256; off <<= 1) {
    int x = sh[t];
    if (t >= off) x += sh[t - off];
    __syncthreads();
    sh[t] = x;
    __syncthreads();
  }
  if (t < nb) bsums[t] = sh[t] - v;
}

__global__ __launch_bounds__(256) void scan3_kernel(int* __restrict__ offs,
                                                    const int* __restrict__ bsums,
                                                    int n, int E) {
  int i = blockIdx.x * 256 + threadIdx.x;
  if (i < n) offs[i] = offs[i] + bsums[i >> 11];
  if (i == 0) offs[n] = E;
}

__global__ __launch_bounds__(256) void scat3_kernel(const int2* __restrict__ inter,
                                                    const int* __restrict__ bstart,
                                                    const int* __restrict__ offs,
                                                    int* __restrict__ csr_src, int n) {
  __shared__ int cur[1024];
  int t = threadIdx.x;
  int b = blockIdx.x;
  int nb0 = b << 10;
  for (int i = t; i < 1024; i += 256) {
    int node = nb0 + i;
    cur[i] = (node < n) ? offs[node] : 0;
  }
  __syncthreads();
  int lo = bstart[b], hi = bstart[b + 1];
  for (int e = lo + t; e < hi; e += 256) {
    int2 sd = inter[e];
    int pos = atomicAdd(&cur[sd.y & 1023], 1);
    csr_src[pos] = sd.x;
  }
}

// W[512][128] fp32 -> fragment-major bf16 hi/lo for direct MFMA B-operand loads.
__global__ __launch_bounds__(256) void wsplit_kernel(const float* __restrict__ W,
                                                     unsigned short* __restrict__ wfh,
                                                     unsigned short* __restrict__ wfl) {
  int i = blockIdx.x * 256 + threadIdx.x;  // 65536 total
  if (i >= IN_C * OUT_C) return;
  int k = i >> 7;
  int col = i & 127;
  float w = W[i];
  __bf16 hb = (__bf16)w;
  __bf16 lb = (__bf16)(w - (float)hb);
  int ks = k >> 5;
  int lg = (k & 31) >> 3;
  int j = k & 7;
  int cb = col >> 4;
  int lane = lg * 16 + (col & 15);
  size_t idx = ((size_t)(ks * 8 + cb) * 64 + lane) * 8 + j;
  wfh[idx] = bfbits(hb);
  wfl[idx] = bfbits(lb);
}

// h = x @ W via 2-term split-bf16 MFMA (x_hi*W_hi + x_hi*W_lo).
// Block: 4 waves (2 row x 2 col); tile 128 rows x 128 cols; BK=32, 16 steps.
// x staged fp32 into double-buffered LDS via global_load_lds (16B), slot-swizzled:
// LDS 16B-slot p=(row,q) holds global k-slot q^(row&7)  [linear dest, inv-swz source].
__global__ __launch_bounds__(256) void gemm_mfma_kernel(
    const float* __restrict__ x, const unsigned short* __restrict__ wfh,
    const unsigned short* __restrict__ wfl, unsigned short* __restrict__ h, int n) {
  __shared__ float xs[2][4096];  // 2 x 16KB: [128 rows][32 k] swizzled

  const int tid = threadIdx.x;
  const int wv = tid >> 6;
  const int lane = tid & 63;
  const int l15 = lane & 15;
  const int lg = lane >> 4;
  const int wr = wv >> 1;
  const int wc = wv & 1;
  const int row0 = blockIdx.x * 128;

  // staging source: thread covers slots p = i*256 + tid (i=0..3); row=p>>3, q=p&7
  const float* gsrc[4];
#pragma unroll
  for (int i = 0; i < 4; i++) {
    int pslot = i * 256 + tid;
    int row = pslot >> 3;
    int q = pslot & 7;
    int s = q ^ (row & 7);
    int grow = row0 + row;
    if (grow > n - 1) grow = n - 1;
    gsrc[i] = x + (size_t)grow * IN_C + s * 4;
  }

  const unsigned short* bph = wfh + ((size_t)(wc * 4) * 64 + lane) * 8;
  const unsigned short* bpl = wfl + ((size_t)(wc * 4) * 64 + lane) * 8;

  f32x4 acc[4][4];
#pragma unroll
  for (int i = 0; i < 4; i++)
#pragma unroll
    for (int j = 0; j < 4; j++) acc[i][j] = (f32x4)0.0f;

  // prologue: stage buf0 (k-step 0)
#pragma unroll
  for (int i = 0; i < 4; i++) {
    char* lp = (char*)&xs[0][0] + i * 4096 + wv * 1024;
    __builtin_amdgcn_global_load_lds(
        (const __attribute__((address_space(1))) void*)gsrc[i],
        (__attribute__((address_space(3))) void*)lp, 16, 0, 0);
    gsrc[i] += 32;
  }
  __syncthreads();

  int cur = 0;
  for (int ks = 0; ks < 16; ks++) {
    if (ks < 15) {
#pragma unroll
      for (int i = 0; i < 4; i++) {
        char* lp = (char*)&xs[cur ^ 1][0] + i * 4096 + wv * 1024;
        __builtin_amdgcn_global_load_lds(
            (const __attribute__((address_space(1))) void*)gsrc[i],
            (__attribute__((address_space(3))) void*)lp, 16, 0, 0);
        gsrc[i] += 32;
      }
    }
    bf16x8 bh[4], bl[4];
#pragma unroll
    for (int nt = 0; nt < 4; nt++) {
      bh[nt] = __builtin_bit_cast(bf16x8, *(const uint4*)(bph + (size_t)ks * 4096 + nt * 512));
      bl[nt] = __builtin_bit_cast(bf16x8, *(const uint4*)(bpl + (size_t)ks * 4096 + nt * 512));
    }
    const float* bp = &xs[cur][0];
    bf16x8 ah[4];
#pragma unroll
    for (int rt = 0; rt < 4; rt++) {
      int row = wr * 64 + rt * 16 + l15;
      int r7 = row & 7;
      int s0 = (lg * 2) ^ r7;
      int s1 = (lg * 2 + 1) ^ r7;
      float4 f0 = *(const float4*)(bp + row * 32 + s0 * 4);  // k = lg*8 .. +3
      float4 f1 = *(const float4*)(bp + row * 32 + s1 * 4);  // k = lg*8+4 .. +7
      float f[8] = {f0.x, f0.y, f0.z, f0.w, f1.x, f1.y, f1.z, f1.w};
      bf16x8 hh;
#pragma unroll
      for (int j = 0; j < 8; j++) hh[j] = (__bf16)f[j];
      ah[rt] = hh;
    }
#pragma unroll
    for (int rt = 0; rt < 4; rt++)
#pragma unroll
      for (int nt = 0; nt < 4; nt++) {
        acc[rt][nt] = __builtin_amdgcn_mfma_f32_16x16x32_bf16(ah[rt], bh[nt], acc[rt][nt], 0, 0, 0);
        acc[rt][nt] = __builtin_amdgcn_mfma_f32_16x16x32_bf16(ah[rt], bl[nt], acc[rt][nt], 0, 0, 0);
      }
    __syncthreads();
    cur ^= 1;
  }

  // store h bf16: D row=(lane>>4)*4+reg, col=lane&15 per 16x16 tile
#pragma unroll
  for (int rt = 0; rt < 4; rt++) {
    int rowbase = row0 + wr * 64 + rt * 16 + lg * 4;
#pragma unroll
    for (int nt = 0; nt < 4; nt++) {
      int col = wc * 64 + nt * 16 + l15;
#pragma unroll
      for (int r = 0; r < 4; r++) {
        int row = rowbase + r;
        if (row < n) h[(size_t)row * OUT_C + col] = bfbits((__bf16)acc[rt][nt][r]);
      }
    }
  }
}

__device__ __forceinline__ float bflo(unsigned int u) {
  return __builtin_bit_cast(float, u << 16);
}
__device__ __forceinline__ float bfhi(unsigned int u) {
  return __builtin_bit_cast(float, u & 0xffff0000u);
}

// One wave per node: out[d] = dinv[d]*(sum_e h[src]*dinv[src] + h[d]*dinv[d]) + b
__global__ __launch_bounds__(256) void gather_kernel(const int* __restrict__ offs,
                                                     const int* __restrict__ csr_src,
                                                     const unsigned int* __restrict__ hp,
                                                     const float* __restrict__ dinv,
                                                     const float* __restrict__ b,
                                                     float* __restrict__ out,
                                                     int n, int tail) {
  int wid = threadIdx.x >> 6;
  int lane = threadIdx.x & 63;
  int node = blockIdx.x * 4 + wid;
  if (node >= n) return;

  int start = offs[node];
  int end = offs[node + 1];

  float accx = 0.0f, accy = 0.0f;
  int e = start;
  for (; e + 4 <= end; e += 4) {
    int s0 = csr_src[e + 0];
    int s1 = csr_src[e + 1];
    int s2 = csr_src[e + 2];
    int s3 = csr_src[e + 3];
    float w0 = dinv[s0], w1 = dinv[s1], w2 = dinv[s2], w3 = dinv[s3];
    unsigned int u0 = hp[(size_t)s0 * 64 + lane];
    unsigned int u1 = hp[(size_t)s1 * 64 + lane];
    unsigned int u2 = hp[(size_t)s2 * 64 + lane];
    unsigned int u3 = hp[(size_t)s3 * 64 + lane];
    accx += bflo(u0) * w0 + bflo(u1) * w1 + bflo(u2) * w2 + bflo(u3) * w3;
    accy += bfhi(u0) * w0 + bfhi(u1) * w1 + bfhi(u2) * w2 + bfhi(u3) * w3;
  }
  for (; e < end; e++) {
    int s = csr_src[e];
    float w = dinv[s];
    unsigned int u = hp[(size_t)s * 64 + lane];
    accx += bflo(u) * w;
    accy += bfhi(u) * w;
  }

  float dd = dinv[node];
  unsigned int us = hp[(size_t)node * 64 + lane];
  accx = (accx + bflo(us) * dd) * dd;
  accy = (accy + bfhi(us) * dd) * dd;
  float2 bb = ((const float2*)b)[lane];
  float2 o = make_float2(accx + bb.x, accy + bb.y);
  ((float2*)out)[(size_t)node * 64 + lane] = o;

  if (node == 0 && lane == 0) {
    for (int t = 0; t < tail; t++) out[(size_t)n * OUT_C + t] = 0.0f;
  }
}

extern "C" void kernel_launch(void* const* d_in, const int* in_sizes, int n_in,
                              void* d_out, int out_size, void* d_ws, size_t ws_size,
                              hipStream_t stream) {
  const float* x = (const float*)d_in[0];
  const int* ei = (const int*)d_in[1];
  const float* W = (const float*)d_in[2];
  const float* b = (const float*)d_in[3];

  const int n = in_sizes[0] / IN_C;
  const int E = in_sizes[1] / 2;
  const int* src = ei;
  const int* dst = ei + E;
  float* out = (float*)d_out;

  const int nchunks = cdiv(E, CHUNK);
  const int nbk = cdiv(n, 1024);

  size_t p = 0;
  auto alloc = [&](size_t bytes) { size_t o = p; p += (bytes + 255) & ~(size_t)255; return o; };
  char* ws = (char*)d_ws;
  float*          dinv   = (float*)(ws + alloc((size_t)n * 4));
  int*            offs   = (int*)(ws + alloc(((size_t)n + 1) * 4));
  int*            csrsrc = (int*)(ws + alloc((size_t)E * 4));
  int*            deg    = (int*)(ws + alloc((size_t)n * 4));
  int*            bsums  = (int*)(ws + alloc(256 * 4));
  int*            bstart = (int*)(ws + alloc((NB + 1) * 4));
  unsigned short* wfh    = (unsigned short*)(ws + alloc((size_t)IN_C * OUT_C * 2));
  unsigned short* wfl    = (unsigned short*)(ws + alloc((size_t)IN_C * OUT_C * 2));
  // union region: {inter + table} (CSR build) then reused as h (GEMM onward)
  size_t upos = p;
  int2*           inter  = (int2*)(ws + upos);
  int*            table  = (int*)(ws + upos + (((size_t)E * 8 + 255) & ~(size_t)255));
  unsigned short* h      = (unsigned short*)(ws + upos);

  const int nb = cdiv(n, SCAN_TILE);

  wsplit_kernel<<<cdiv(IN_C * OUT_C, 256), 256, 0, stream>>>(W, wfh, wfl);
  hist_kernel<<<nchunks, 256, 0, stream>>>(dst, table, nchunks, E);
  tscan_kernel<<<1, 256, 0, stream>>>(table, bstart, nchunks, E);
  scat2_kernel<<<nchunks, 256, 0, stream>>>(src, dst, table, inter, nchunks, E);
  bdeg_kernel<<<nbk, 256, 0, stream>>>(inter, bstart, deg, n);
  dinv_kernel<<<cdiv(n, 256), 256, 0, stream>>>(deg, dinv, n);
  scan1_kernel<<<nb, 256, 0, stream>>>(deg, offs, bsums, n);
  scan2_kernel<<<1, 256, 0, stream>>>(bsums, nb);
  scan3_kernel<<<cdiv(n, 256), 256, 0, stream>>>(offs, bsums, n, E);
  scat3_kernel<<<nbk, 256, 0, stream>>>(inter, bstart, offs, csrsrc, n);
  gemm_mfma_kernel<<<cdiv(n, 128), 256, 0, stream>>>(x, wfh, wfl, h, n);
  int tail = out_size - n * OUT_C;
  gather_kernel<<<cdiv(n, 4), 256, 0, stream>>>(offs, csrsrc, (const unsigned int*)h, dinv, b, out, n, tail);
}

// Round 8
// 277.558 us; speedup vs baseline: 10.6531x; 1.0380x over previous
//
#include <hip/hip_runtime.h>

#define IN_C 512
#define OUT_C 128
#define SCAN_TILE 2048
#define NB 128          // dst buckets (dst >> 10)
#define CHUNK 8192      // edges per histogram/scatter chunk

typedef float f32x4 __attribute__((ext_vector_type(4)));
typedef __bf16 bf16x8 __attribute__((ext_vector_type(8)));

static inline int cdiv(int a, int b) { return (a + b - 1) / b; }

__device__ __forceinline__ unsigned short bfbits(__bf16 h) {
  return __builtin_bit_cast(unsigned short, h);
}

// ---- CSR build: two-level counting sort (no global atomics) ----

__global__ __launch_bounds__(256) void hist_kernel(const int* __restrict__ dst,
                                                   int* __restrict__ table,
                                                   int nchunks, int E) {
  __shared__ int hcnt[NB];
  int t = threadIdx.x;
  int c = blockIdx.x;
  if (t < NB) hcnt[t] = 0;
  __syncthreads();
  int base = c * CHUNK;
  for (int i = t; i < CHUNK; i += 256) {
    int e = base + i;
    if (e < E) atomicAdd(&hcnt[dst[e] >> 10], 1);
  }
  __syncthreads();
  if (t < NB) table[t * nchunks + c] = hcnt[t];
}

__global__ __launch_bounds__(256) void tscan_kernel(int* __restrict__ table,
                                                    int* __restrict__ bstart,
                                                    int nchunks, int E) {
  __shared__ int sh[256];
  int t = threadIdx.x;
  int total = NB * nchunks;
  int S = (total + 255) / 256;
  int lo = t * S;
  int hi = lo + S; if (hi > total) hi = total;
  int s = 0;
  int i = lo;
  for (; i + 4 <= hi; i += 4)
    s += table[i] + table[i + 1] + table[i + 2] + table[i + 3];
  for (; i < hi; i++) s += table[i];
  sh[t] = s;
  __syncthreads();
  for (int off = 1; off < 256; off <<= 1) {
    int x = sh[t];
    if (t >= off) x += sh[t - off];
    __syncthreads();
    sh[t] = x;
    __syncthreads();
  }
  int run = sh[t] - s;
  for (i = lo; i < hi; i++) {
    int v = table[i];
    table[i] = run;
    run += v;
  }
  __syncthreads();
  for (int b = t; b < NB; b += 256) bstart[b] = table[b * nchunks];
  if (t == 0) bstart[NB] = E;
}

__global__ __launch_bounds__(256) void scat2_kernel(const int* __restrict__ src,
                                                    const int* __restrict__ dst,
                                                    const int* __restrict__ table,
                                                    int2* __restrict__ inter,
                                                    int nchunks, int E) {
  __shared__ int cur[NB];
  int t = threadIdx.x;
  int c = blockIdx.x;
  if (t < NB) cur[t] = table[t * nchunks + c];
  __syncthreads();
  int base = c * CHUNK;
  for (int i = t; i < CHUNK; i += 256) {
    int e = base + i;
    if (e < E) {
      int d = dst[e];
      int pos = atomicAdd(&cur[d >> 10], 1);
      inter[pos] = make_int2(src[e], d);
    }
  }
}

__global__ __launch_bounds__(256) void bdeg_kernel(const int2* __restrict__ inter,
                                                   const int* __restrict__ bstart,
                                                   int* __restrict__ deg, int n) {
  __shared__ int dl[1024];
  int t = threadIdx.x;
  int b = blockIdx.x;
  for (int i = t; i < 1024; i += 256) dl[i] = 0;
  __syncthreads();
  int lo = bstart[b], hi = bstart[b + 1];
  for (int e = lo + t; e < hi; e += 256) atomicAdd(&dl[inter[e].y & 1023], 1);
  __syncthreads();
  int nb0 = b << 10;
  for (int i = t; i < 1024; i += 256) {
    int node = nb0 + i;
    if (node < n) deg[node] = dl[i];
  }
}

__global__ __launch_bounds__(256) void dinv_kernel(const int* __restrict__ deg,
                                                   float* __restrict__ dinv, int n) {
  int i = blockIdx.x * 256 + threadIdx.x;
  if (i < n) dinv[i] = rsqrtf((float)deg[i] + 1.0f);
}

// ---- 3-phase exclusive scan of deg -> offs ----
__global__ __launch_bounds__(256) void scan1_kernel(const int* __restrict__ deg,
                                                    int* __restrict__ offs,
                                                    int* __restrict__ bsums, int n) {
  __shared__ int sh[256];
  int t = threadIdx.x;
  int base = blockIdx.x * SCAN_TILE + t * 8;
  int v[8];
  int s = 0;
#pragma unroll
  for (int i = 0; i < 8; i++) {
    int idx = base + i;
    v[i] = (idx < n) ? deg[idx] : 0;
    s += v[i];
  }
  sh[t] = s;
  __syncthreads();
  for (int off = 1; off < 256; off <<= 1) {
    int x = sh[t];
    if (t >= off) x += sh[t - off];
    __syncthreads();
    sh[t] = x;
    __syncthreads();
  }
  int run = sh[t] - s;
#pragma unroll
  for (int i = 0; i < 8; i++) {
    int idx = base + i;
    if (idx < n) offs[idx] = run;
    run += v[i];
  }
  if (t == 255) bsums[blockIdx.x] = sh[255];
}

__global__ __launch_bounds__(256) void scan2_kernel(int* __restrict__ bsums, int nb) {
  __shared__ int sh[256];
  int t = threadIdx.x;
  int v = (t < nb) ? bsums[t] : 0;
  sh[t] = v;
  __syncthreads();
  for (int off = 1; off < 256; off <<= 1) {
    int x = sh[t];
    if (t >= off) x += sh[t - off];
    __syncthreads();
    sh[t] = x;
    __syncthreads();
  }
  if (t < nb) bsums[t] = sh[t] - v;
}

__global__ __launch_bounds__(256) void scan3_kernel(int* __restrict__ offs,
                                                    const int* __restrict__ bsums,
                                                    int n, int E) {
  int i = blockIdx.x * 256 + threadIdx.x;
  if (i < n) offs[i] = offs[i] + bsums[i >> 11];
  if (i == 0) offs[n] = E;
}

__global__ __launch_bounds__(256) void scat3_kernel(const int2* __restrict__ inter,
                                                    const int* __restrict__ bstart,
                                                    const int* __restrict__ offs,
                                                    int* __restrict__ csr_src, int n) {
  __shared__ int cur[1024];
  int t = threadIdx.x;
  int b = blockIdx.x;
  int nb0 = b << 10;
  for (int i = t; i < 1024; i += 256) {
    int node = nb0 + i;
    cur[i] = (node < n) ? offs[node] : 0;
  }
  __syncthreads();
  int lo = bstart[b], hi = bstart[b + 1];
  for (int e = lo + t; e < hi; e += 256) {
    int2 sd = inter[e];
    int pos = atomicAdd(&cur[sd.y & 1023], 1);
    csr_src[pos] = sd.x;
  }
}

// W[512][128] fp32 -> fragment-major bf16 hi/lo for direct MFMA B-operand loads.
__global__ __launch_bounds__(256) void wsplit_kernel(const float* __restrict__ W,
                                                     unsigned short* __restrict__ wfh,
                                                     unsigned short* __restrict__ wfl) {
  int i = blockIdx.x * 256 + threadIdx.x;  // 65536 total
  if (i >= IN_C * OUT_C) return;
  int k = i >> 7;
  int col = i & 127;
  float w = W[i];
  __bf16 hb = (__bf16)w;
  __bf16 lb = (__bf16)(w - (float)hb);
  int ks = k >> 5;
  int lg = (k & 31) >> 3;
  int j = k & 7;
  int cb = col >> 4;
  int lane = lg * 16 + (col & 15);
  size_t idx = ((size_t)(ks * 8 + cb) * 64 + lane) * 8 + j;
  wfh[idx] = bfbits(hb);
  wfl[idx] = bfbits(lb);
}

// h = x @ W via 2-term split-bf16 MFMA (x_hi*W_hi + x_hi*W_lo).
// Block: 4 waves (2 row x 2 col); tile 128 rows x 128 cols; BK=32, 16 steps.
// x staged fp32 into double-buffered LDS via global_load_lds (16B), slot-swizzled.
__global__ __launch_bounds__(256) void gemm_mfma_kernel(
    const float* __restrict__ x, const unsigned short* __restrict__ wfh,
    const unsigned short* __restrict__ wfl, unsigned short* __restrict__ h, int n) {
  __shared__ float xs[2][4096];  // 2 x 16KB: [128 rows][32 k] swizzled

  const int tid = threadIdx.x;
  const int wv = tid >> 6;
  const int lane = tid & 63;
  const int l15 = lane & 15;
  const int lg = lane >> 4;
  const int wr = wv >> 1;
  const int wc = wv & 1;
  const int row0 = blockIdx.x * 128;

  const float* gsrc[4];
#pragma unroll
  for (int i = 0; i < 4; i++) {
    int pslot = i * 256 + tid;
    int row = pslot >> 3;
    int q = pslot & 7;
    int s = q ^ (row & 7);
    int grow = row0 + row;
    if (grow > n - 1) grow = n - 1;
    gsrc[i] = x + (size_t)grow * IN_C + s * 4;
  }

  const unsigned short* bph = wfh + ((size_t)(wc * 4) * 64 + lane) * 8;
  const unsigned short* bpl = wfl + ((size_t)(wc * 4) * 64 + lane) * 8;

  f32x4 acc[4][4];
#pragma unroll
  for (int i = 0; i < 4; i++)
#pragma unroll
    for (int j = 0; j < 4; j++) acc[i][j] = (f32x4)0.0f;

#pragma unroll
  for (int i = 0; i < 4; i++) {
    char* lp = (char*)&xs[0][0] + i * 4096 + wv * 1024;
    __builtin_amdgcn_global_load_lds(
        (const __attribute__((address_space(1))) void*)gsrc[i],
        (__attribute__((address_space(3))) void*)lp, 16, 0, 0);
    gsrc[i] += 32;
  }
  __syncthreads();

  int cur = 0;
  for (int ks = 0; ks < 16; ks++) {
    if (ks < 15) {
#pragma unroll
      for (int i = 0; i < 4; i++) {
        char* lp = (char*)&xs[cur ^ 1][0] + i * 4096 + wv * 1024;
        __builtin_amdgcn_global_load_lds(
            (const __attribute__((address_space(1))) void*)gsrc[i],
            (__attribute__((address_space(3))) void*)lp, 16, 0, 0);
        gsrc[i] += 32;
      }
    }
    bf16x8 bh[4], bl[4];
#pragma unroll
    for (int nt = 0; nt < 4; nt++) {
      bh[nt] = __builtin_bit_cast(bf16x8, *(const uint4*)(bph + (size_t)ks * 4096 + nt * 512));
      bl[nt] = __builtin_bit_cast(bf16x8, *(const uint4*)(bpl + (size_t)ks * 4096 + nt * 512));
    }
    const float* bp = &xs[cur][0];
    bf16x8 ah[4];
#pragma unroll
    for (int rt = 0; rt < 4; rt++) {
      int row = wr * 64 + rt * 16 + l15;
      int r7 = row & 7;
      int s0 = (lg * 2) ^ r7;
      int s1 = (lg * 2 + 1) ^ r7;
      float4 f0 = *(const float4*)(bp + row * 32 + s0 * 4);
      float4 f1 = *(const float4*)(bp + row * 32 + s1 * 4);
      float f[8] = {f0.x, f0.y, f0.z, f0.w, f1.x, f1.y, f1.z, f1.w};
      bf16x8 hh;
#pragma unroll
      for (int j = 0; j < 8; j++) hh[j] = (__bf16)f[j];
      ah[rt] = hh;
    }
#pragma unroll
    for (int rt = 0; rt < 4; rt++)
#pragma unroll
      for (int nt = 0; nt < 4; nt++) {
        acc[rt][nt] = __builtin_amdgcn_mfma_f32_16x16x32_bf16(ah[rt], bh[nt], acc[rt][nt], 0, 0, 0);
        acc[rt][nt] = __builtin_amdgcn_mfma_f32_16x16x32_bf16(ah[rt], bl[nt], acc[rt][nt], 0, 0, 0);
      }
    __syncthreads();
    cur ^= 1;
  }

#pragma unroll
  for (int rt = 0; rt < 4; rt++) {
    int rowbase = row0 + wr * 64 + rt * 16 + lg * 4;
#pragma unroll
    for (int nt = 0; nt < 4; nt++) {
      int col = wc * 64 + nt * 16 + l15;
#pragma unroll
      for (int r = 0; r < 4; r++) {
        int row = rowbase + r;
        if (row < n) h[(size_t)row * OUT_C + col] = bfbits((__bf16)acc[rt][nt][r]);
      }
    }
  }
}

__device__ __forceinline__ float bflo(unsigned int u) {
  return __builtin_bit_cast(float, u << 16);
}
__device__ __forceinline__ float bfhi(unsigned int u) {
  return __builtin_bit_cast(float, u & 0xffff0000u);
}

// Gather, quarter-wave edge-parallel: one node per wave, each 16-lane quarter
// owns one edge; lane loads uint4 (8 bf16 cols). 4 edges/issue = 1KB coalesced.
// out[d] = dinv[d]*(sum_e h[src]*dinv[src] + h[d]*dinv[d]) + b
__global__ __launch_bounds__(256) void gather_kernel(const int* __restrict__ offs,
                                                     const int* __restrict__ csr_src,
                                                     const unsigned short* __restrict__ h,
                                                     const float* __restrict__ dinv,
                                                     const float* __restrict__ b,
                                                     float* __restrict__ out,
                                                     int n, int tail) {
  int wid = threadIdx.x >> 6;
  int lane = threadIdx.x & 63;
  int l15 = lane & 15;
  int q = lane >> 4;  // quarter 0..3
  int node = blockIdx.x * 4 + wid;
  if (node >= n) return;

  int start = offs[node];
  int end = offs[node + 1];

  // acc[t]: cols l15*8 + 2t (x) and +2t+1 (y)
  float ax0 = 0, ay0 = 0, ax1 = 0, ay1 = 0, ax2 = 0, ay2 = 0, ax3 = 0, ay3 = 0;

  int e = start + q;
  // unrolled x2: two outstanding rows per quarter
  for (; e + 4 < end; e += 8) {
    int s0 = csr_src[e];
    int s1 = csr_src[e + 4];
    float w0 = dinv[s0];
    float w1 = dinv[s1];
    uint4 u0 = *(const uint4*)(h + (size_t)s0 * OUT_C + l15 * 8);
    uint4 u1 = *(const uint4*)(h + (size_t)s1 * OUT_C + l15 * 8);
    ax0 += bflo(u0.x) * w0 + bflo(u1.x) * w1;
    ay0 += bfhi(u0.x) * w0 + bfhi(u1.x) * w1;
    ax1 += bflo(u0.y) * w0 + bflo(u1.y) * w1;
    ay1 += bfhi(u0.y) * w0 + bfhi(u1.y) * w1;
    ax2 += bflo(u0.z) * w0 + bflo(u1.z) * w1;
    ay2 += bfhi(u0.z) * w0 + bfhi(u1.z) * w1;
    ax3 += bflo(u0.w) * w0 + bflo(u1.w) * w1;
    ay3 += bfhi(u0.w) * w0 + bfhi(u1.w) * w1;
  }
  if (e < end) {
    int s0 = csr_src[e];
    float w0 = dinv[s0];
    uint4 u0 = *(const uint4*)(h + (size_t)s0 * OUT_C + l15 * 8);
    ax0 += bflo(u0.x) * w0; ay0 += bfhi(u0.x) * w0;
    ax1 += bflo(u0.y) * w0; ay1 += bfhi(u0.y) * w0;
    ax2 += bflo(u0.z) * w0; ay2 += bfhi(u0.z) * w0;
    ax3 += bflo(u0.w) * w0; ay3 += bfhi(u0.w) * w0;
  }

  // butterfly-reduce across quarters (masks 16, 32): all lanes end identical
#pragma unroll
  for (int mask = 16; mask <= 32; mask <<= 1) {
    ax0 += __shfl_xor(ax0, mask); ay0 += __shfl_xor(ay0, mask);
    ax1 += __shfl_xor(ax1, mask); ay1 += __shfl_xor(ay1, mask);
    ax2 += __shfl_xor(ax2, mask); ay2 += __shfl_xor(ay2, mask);
    ax3 += __shfl_xor(ax3, mask); ay3 += __shfl_xor(ay3, mask);
  }

  // self term + scale + bias (uniform across lanes)
  float dd = dinv[node];
  uint4 us = *(const uint4*)(h + (size_t)node * OUT_C + l15 * 8);
  ax0 = (ax0 + bflo(us.x) * dd) * dd; ay0 = (ay0 + bfhi(us.x) * dd) * dd;
  ax1 = (ax1 + bflo(us.y) * dd) * dd; ay1 = (ay1 + bfhi(us.y) * dd) * dd;
  ax2 = (ax2 + bflo(us.z) * dd) * dd; ay2 = (ay2 + bfhi(us.z) * dd) * dd;
  ax3 = (ax3 + bflo(us.w) * dd) * dd; ay3 = (ay3 + bfhi(us.w) * dd) * dd;

  if (q == 0) {
    float4 b0 = *(const float4*)(b + l15 * 8);
    float4 b1 = *(const float4*)(b + l15 * 8 + 4);
    float4 o0 = make_float4(ax0 + b0.x, ay0 + b0.y, ax1 + b0.z, ay1 + b0.w);
    float4 o1 = make_float4(ax2 + b1.x, ay2 + b1.y, ax3 + b1.z, ay3 + b1.w);
    float* op = out + (size_t)node * OUT_C + l15 * 8;
    *(float4*)op = o0;
    *(float4*)(op + 4) = o1;
  }

  if (node == 0 && lane == 0) {
    for (int t = 0; t < tail; t++) out[(size_t)n * OUT_C + t] = 0.0f;
  }
}

extern "C" void kernel_launch(void* const* d_in, const int* in_sizes, int n_in,
                              void* d_out, int out_size, void* d_ws, size_t ws_size,
                              hipStream_t stream) {
  const float* x = (const float*)d_in[0];
  const int* ei = (const int*)d_in[1];
  const float* W = (const float*)d_in[2];
  const float* b = (const float*)d_in[3];

  const int n = in_sizes[0] / IN_C;
  const int E = in_sizes[1] / 2;
  const int* src = ei;
  const int* dst = ei + E;
  float* out = (float*)d_out;

  const int nchunks = cdiv(E, CHUNK);
  const int nbk = cdiv(n, 1024);

  size_t p = 0;
  auto alloc = [&](size_t bytes) { size_t o = p; p += (bytes + 255) & ~(size_t)255; return o; };
  char* ws = (char*)d_ws;
  float*          dinv   = (float*)(ws + alloc((size_t)n * 4));
  int*            offs   = (int*)(ws + alloc(((size_t)n + 1) * 4));
  int*            csrsrc = (int*)(ws + alloc((size_t)E * 4));
  int*            deg    = (int*)(ws + alloc((size_t)n * 4));
  int*            bsums  = (int*)(ws + alloc(256 * 4));
  int*            bstart = (int*)(ws + alloc((NB + 1) * 4));
  unsigned short* wfh    = (unsigned short*)(ws + alloc((size_t)IN_C * OUT_C * 2));
  unsigned short* wfl    = (unsigned short*)(ws + alloc((size_t)IN_C * OUT_C * 2));
  size_t upos = p;
  int2*           inter  = (int2*)(ws + upos);
  int*            table  = (int*)(ws + upos + (((size_t)E * 8 + 255) & ~(size_t)255));
  unsigned short* h      = (unsigned short*)(ws + upos);

  const int nb = cdiv(n, SCAN_TILE);

  wsplit_kernel<<<cdiv(IN_C * OUT_C, 256), 256, 0, stream>>>(W, wfh, wfl);
  hist_kernel<<<nchunks, 256, 0, stream>>>(dst, table, nchunks, E);
  tscan_kernel<<<1, 256, 0, stream>>>(table, bstart, nchunks, E);
  scat2_kernel<<<nchunks, 256, 0, stream>>>(src, dst, table, inter, nchunks, E);
  bdeg_kernel<<<nbk, 256, 0, stream>>>(inter, bstart, deg, n);
  dinv_kernel<<<cdiv(n, 256), 256, 0, stream>>>(deg, dinv, n);
  scan1_kernel<<<nb, 256, 0, stream>>>(deg, offs, bsums, n);
  scan2_kernel<<<1, 256, 0, stream>>>(bsums, nb);
  scan3_kernel<<<cdiv(n, 256), 256, 0, stream>>>(offs, bsums, n, E);
  scat3_kernel<<<nbk, 256, 0, stream>>>(inter, bstart, offs, csrsrc, n);
  gemm_mfma_kernel<<<cdiv(n, 128), 256, 0, stream>>>(x, wfh, wfl, h, n);
  int tail = out_size - n * OUT_C;
  gather_kernel<<<cdiv(n, 4), 256, 0, stream>>>(offs, csrsrc, h, dinv, b, out, n, tail);
}

// Round 9
// 268.413 us; speedup vs baseline: 11.0161x; 1.0341x over previous
//
#include <hip/hip_runtime.h>

#define IN_C 512
#define OUT_C 128
#define NB 128          // dst buckets (dst >> 10)
#define CHUNK 8192      // edges per histogram/scatter chunk

typedef float f32x4 __attribute__((ext_vector_type(4)));
typedef __bf16 bf16x8 __attribute__((ext_vector_type(8)));

static inline int cdiv(int a, int b) { return (a + b - 1) / b; }

__device__ __forceinline__ unsigned short bfbits(__bf16 h) {
  return __builtin_bit_cast(unsigned short, h);
}

// ---- CSR build: two-level counting sort (no global atomics) ----

__global__ __launch_bounds__(256) void hist_kernel(const int* __restrict__ dst,
                                                   int* __restrict__ table,
                                                   int nchunks, int E) {
  __shared__ int hcnt[NB];
  int t = threadIdx.x;
  int c = blockIdx.x;
  if (t < NB) hcnt[t] = 0;
  __syncthreads();
  int base = c * CHUNK;
  for (int i = t; i < CHUNK; i += 256) {
    int e = base + i;
    if (e < E) atomicAdd(&hcnt[dst[e] >> 10], 1);
  }
  __syncthreads();
  if (t < NB) table[t * nchunks + c] = hcnt[t];
}

__global__ __launch_bounds__(256) void tscan_kernel(int* __restrict__ table,
                                                    int* __restrict__ bstart,
                                                    int nchunks, int E) {
  __shared__ int sh[256];
  int t = threadIdx.x;
  int total = NB * nchunks;
  int S = (total + 255) / 256;
  int lo = t * S;
  int hi = lo + S; if (hi > total) hi = total;
  int s = 0;
  int i = lo;
  for (; i + 4 <= hi; i += 4)
    s += table[i] + table[i + 1] + table[i + 2] + table[i + 3];
  for (; i < hi; i++) s += table[i];
  sh[t] = s;
  __syncthreads();
  for (int off = 1; off < 256; off <<= 1) {
    int x = sh[t];
    if (t >= off) x += sh[t - off];
    __syncthreads();
    sh[t] = x;
    __syncthreads();
  }
  int run = sh[t] - s;
  for (i = lo; i < hi; i++) {
    int v = table[i];
    table[i] = run;
    run += v;
  }
  __syncthreads();
  for (int b = t; b < NB; b += 256) bstart[b] = table[b * nchunks];
  if (t == 0) bstart[NB] = E;
}

// scatter edges into bucket-major packed inter[]: (src<<10) | (dst&1023)
__global__ __launch_bounds__(256) void scat2_kernel(const int* __restrict__ src,
                                                    const int* __restrict__ dst,
                                                    const int* __restrict__ table,
                                                    int* __restrict__ inter,
                                                    int nchunks, int E) {
  __shared__ int cur[NB];
  int t = threadIdx.x;
  int c = blockIdx.x;
  if (t < NB) cur[t] = table[t * nchunks + c];
  __syncthreads();
  int base = c * CHUNK;
  for (int i = t; i < CHUNK; i += 256) {
    int e = base + i;
    if (e < E) {
      int d = dst[e];
      int pos = atomicAdd(&cur[d >> 10], 1);
      inter[pos] = (src[e] << 10) | (d & 1023);
    }
  }
}

// per-bucket: degree count + dinv + CSR offsets (bstart[b] + in-bucket scan)
__global__ __launch_bounds__(256) void bdeg_offs_kernel(const int* __restrict__ inter,
                                                        const int* __restrict__ bstart,
                                                        int* __restrict__ offs,
                                                        float* __restrict__ dinv,
                                                        int n, int E, int nbk) {
  __shared__ int dl[1024];
  __shared__ int sh[256];
  int t = threadIdx.x;
  int b = blockIdx.x;
  for (int i = t; i < 1024; i += 256) dl[i] = 0;
  __syncthreads();
  int lo = bstart[b], hi = bstart[b + 1];
  for (int e = lo + t; e < hi; e += 256) atomicAdd(&dl[inter[e] & 1023], 1);
  __syncthreads();
  int c[4];
  int s = 0;
#pragma unroll
  for (int j = 0; j < 4; j++) {
    c[j] = dl[t * 4 + j];
    s += c[j];
  }
  sh[t] = s;
  __syncthreads();
  for (int off = 1; off < 256; off <<= 1) {
    int x = sh[t];
    if (t >= off) x += sh[t - off];
    __syncthreads();
    sh[t] = x;
    __syncthreads();
  }
  int run = sh[t] - s + lo;
  int nb0 = b << 10;
#pragma unroll
  for (int j = 0; j < 4; j++) {
    int node = nb0 + t * 4 + j;
    if (node < n) {
      offs[node] = run;
      dinv[node] = rsqrtf((float)c[j] + 1.0f);
    }
    run += c[j];
  }
  if (b == nbk - 1 && t == 255) offs[n] = E;
}

__global__ __launch_bounds__(256) void scat3_kernel(const int* __restrict__ inter,
                                                    const int* __restrict__ bstart,
                                                    const int* __restrict__ offs,
                                                    int* __restrict__ csr_src, int n) {
  __shared__ int cur[1024];
  int t = threadIdx.x;
  int b = blockIdx.x;
  int nb0 = b << 10;
  for (int i = t; i < 1024; i += 256) {
    int node = nb0 + i;
    cur[i] = (node < n) ? offs[node] : 0;
  }
  __syncthreads();
  int lo = bstart[b], hi = bstart[b + 1];
  for (int e = lo + t; e < hi; e += 256) {
    int u = inter[e];
    int pos = atomicAdd(&cur[u & 1023], 1);
    csr_src[pos] = u >> 10;
  }
}

// W[512][128] fp32 -> fragment-major bf16 hi/lo for direct MFMA B-operand loads.
__global__ __launch_bounds__(256) void wsplit_kernel(const float* __restrict__ W,
                                                     unsigned short* __restrict__ wfh,
                                                     unsigned short* __restrict__ wfl) {
  int i = blockIdx.x * 256 + threadIdx.x;  // 65536 total
  if (i >= IN_C * OUT_C) return;
  int k = i >> 7;
  int col = i & 127;
  float w = W[i];
  __bf16 hb = (__bf16)w;
  __bf16 lb = (__bf16)(w - (float)hb);
  int ks = k >> 5;
  int lg = (k & 31) >> 3;
  int j = k & 7;
  int cb = col >> 4;
  int lane = lg * 16 + (col & 15);
  size_t idx = ((size_t)(ks * 8 + cb) * 64 + lane) * 8 + j;
  wfh[idx] = bfbits(hb);
  wfl[idx] = bfbits(lb);
}

// h2[i][:] = bf16( (x @ W)[i][:] * dinv[i] )  — pre-scaled by source norm.
// 2-term split-bf16 MFMA; 4 waves (2x2); tile 128x128; BK=32 double-buffered
// LDS via global_load_lds (16B slots, XOR-swizzled source).
__global__ __launch_bounds__(256) void gemm_mfma_kernel(
    const float* __restrict__ x, const unsigned short* __restrict__ wfh,
    const unsigned short* __restrict__ wfl, const float* __restrict__ dinv,
    unsigned short* __restrict__ h, int n) {
  __shared__ float xs[2][4096];  // 2 x 16KB: [128 rows][32 k] swizzled

  const int tid = threadIdx.x;
  const int wv = tid >> 6;
  const int lane = tid & 63;
  const int l15 = lane & 15;
  const int lg = lane >> 4;
  const int wr = wv >> 1;
  const int wc = wv & 1;
  const int row0 = blockIdx.x * 128;

  const float* gsrc[4];
#pragma unroll
  for (int i = 0; i < 4; i++) {
    int pslot = i * 256 + tid;
    int row = pslot >> 3;
    int q = pslot & 7;
    int s = q ^ (row & 7);
    int grow = row0 + row;
    if (grow > n - 1) grow = n - 1;
    gsrc[i] = x + (size_t)grow * IN_C + s * 4;
  }

  const unsigned short* bph = wfh + ((size_t)(wc * 4) * 64 + lane) * 8;
  const unsigned short* bpl = wfl + ((size_t)(wc * 4) * 64 + lane) * 8;

  f32x4 acc[4][4];
#pragma unroll
  for (int i = 0; i < 4; i++)
#pragma unroll
    for (int j = 0; j < 4; j++) acc[i][j] = (f32x4)0.0f;

#pragma unroll
  for (int i = 0; i < 4; i++) {
    char* lp = (char*)&xs[0][0] + i * 4096 + wv * 1024;
    __builtin_amdgcn_global_load_lds(
        (const __attribute__((address_space(1))) void*)gsrc[i],
        (__attribute__((address_space(3))) void*)lp, 16, 0, 0);
    gsrc[i] += 32;
  }
  __syncthreads();

  int cur = 0;
  for (int ks = 0; ks < 16; ks++) {
    if (ks < 15) {
#pragma unroll
      for (int i = 0; i < 4; i++) {
        char* lp = (char*)&xs[cur ^ 1][0] + i * 4096 + wv * 1024;
        __builtin_amdgcn_global_load_lds(
            (const __attribute__((address_space(1))) void*)gsrc[i],
            (__attribute__((address_space(3))) void*)lp, 16, 0, 0);
        gsrc[i] += 32;
      }
    }
    bf16x8 bh[4], bl[4];
#pragma unroll
    for (int nt = 0; nt < 4; nt++) {
      bh[nt] = __builtin_bit_cast(bf16x8, *(const uint4*)(bph + (size_t)ks * 4096 + nt * 512));
      bl[nt] = __builtin_bit_cast(bf16x8, *(const uint4*)(bpl + (size_t)ks * 4096 + nt * 512));
    }
    const float* bp = &xs[cur][0];
    bf16x8 ah[4];
#pragma unroll
    for (int rt = 0; rt < 4; rt++) {
      int row = wr * 64 + rt * 16 + l15;
      int r7 = row & 7;
      int s0 = (lg * 2) ^ r7;
      int s1 = (lg * 2 + 1) ^ r7;
      float4 f0 = *(const float4*)(bp + row * 32 + s0 * 4);
      float4 f1 = *(const float4*)(bp + row * 32 + s1 * 4);
      float f[8] = {f0.x, f0.y, f0.z, f0.w, f1.x, f1.y, f1.z, f1.w};
      bf16x8 hh;
#pragma unroll
      for (int j = 0; j < 8; j++) hh[j] = (__bf16)f[j];
      ah[rt] = hh;
    }
#pragma unroll
    for (int rt = 0; rt < 4; rt++)
#pragma unroll
      for (int nt = 0; nt < 4; nt++) {
        acc[rt][nt] = __builtin_amdgcn_mfma_f32_16x16x32_bf16(ah[rt], bh[nt], acc[rt][nt], 0, 0, 0);
        acc[rt][nt] = __builtin_amdgcn_mfma_f32_16x16x32_bf16(ah[rt], bl[nt], acc[rt][nt], 0, 0, 0);
      }
    __syncthreads();
    cur ^= 1;
  }

#pragma unroll
  for (int rt = 0; rt < 4; rt++) {
    int rowbase = row0 + wr * 64 + rt * 16 + lg * 4;
#pragma unroll
    for (int r = 0; r < 4; r++) {
      int row = rowbase + r;
      if (row < n) {
        float di = dinv[row];
#pragma unroll
        for (int nt = 0; nt < 4; nt++) {
          int col = wc * 64 + nt * 16 + l15;
          h[(size_t)row * OUT_C + col] = bfbits((__bf16)(acc[rt][nt][r] * di));
        }
      }
    }
  }
}

__device__ __forceinline__ float bflo(unsigned int u) {
  return __builtin_bit_cast(float, u << 16);
}
__device__ __forceinline__ float bfhi(unsigned int u) {
  return __builtin_bit_cast(float, u & 0xffff0000u);
}

// Gather (h2 pre-scaled): out[d] = dinv[d]*(sum_e h2[src_e] + h2[d]) + b.
// One node per wave; each 16-lane quarter owns one edge; lane loads uint4.
__global__ __launch_bounds__(256) void gather_kernel(const int* __restrict__ offs,
                                                     const int* __restrict__ csr_src,
                                                     const unsigned short* __restrict__ h,
                                                     const float* __restrict__ dinv,
                                                     const float* __restrict__ b,
                                                     float* __restrict__ out,
                                                     int n, int tail) {
  int wid = threadIdx.x >> 6;
  int lane = threadIdx.x & 63;
  int l15 = lane & 15;
  int q = lane >> 4;  // quarter 0..3
  int node = blockIdx.x * 4 + wid;
  if (node >= n) return;

  int start = offs[node];
  int end = offs[node + 1];

  float ax0 = 0, ay0 = 0, ax1 = 0, ay1 = 0, ax2 = 0, ay2 = 0, ax3 = 0, ay3 = 0;

  int e = start + q;
  for (; e + 4 < end; e += 8) {
    int s0 = csr_src[e];
    int s1 = csr_src[e + 4];
    uint4 u0 = *(const uint4*)(h + (size_t)s0 * OUT_C + l15 * 8);
    uint4 u1 = *(const uint4*)(h + (size_t)s1 * OUT_C + l15 * 8);
    ax0 += bflo(u0.x) + bflo(u1.x); ay0 += bfhi(u0.x) + bfhi(u1.x);
    ax1 += bflo(u0.y) + bflo(u1.y); ay1 += bfhi(u0.y) + bfhi(u1.y);
    ax2 += bflo(u0.z) + bflo(u1.z); ay2 += bfhi(u0.z) + bfhi(u1.z);
    ax3 += bflo(u0.w) + bflo(u1.w); ay3 += bfhi(u0.w) + bfhi(u1.w);
  }
  if (e < end) {
    int s0 = csr_src[e];
    uint4 u0 = *(const uint4*)(h + (size_t)s0 * OUT_C + l15 * 8);
    ax0 += bflo(u0.x); ay0 += bfhi(u0.x);
    ax1 += bflo(u0.y); ay1 += bfhi(u0.y);
    ax2 += bflo(u0.z); ay2 += bfhi(u0.z);
    ax3 += bflo(u0.w); ay3 += bfhi(u0.w);
  }

#pragma unroll
  for (int mask = 16; mask <= 32; mask <<= 1) {
    ax0 += __shfl_xor(ax0, mask); ay0 += __shfl_xor(ay0, mask);
    ax1 += __shfl_xor(ax1, mask); ay1 += __shfl_xor(ay1, mask);
    ax2 += __shfl_xor(ax2, mask); ay2 += __shfl_xor(ay2, mask);
    ax3 += __shfl_xor(ax3, mask); ay3 += __shfl_xor(ay3, mask);
  }

  float dd = dinv[node];
  uint4 us = *(const uint4*)(h + (size_t)node * OUT_C + l15 * 8);
  ax0 = (ax0 + bflo(us.x)) * dd; ay0 = (ay0 + bfhi(us.x)) * dd;
  ax1 = (ax1 + bflo(us.y)) * dd; ay1 = (ay1 + bfhi(us.y)) * dd;
  ax2 = (ax2 + bflo(us.z)) * dd; ay2 = (ay2 + bfhi(us.z)) * dd;
  ax3 = (ax3 + bflo(us.w)) * dd; ay3 = (ay3 + bfhi(us.w)) * dd;

  if (q == 0) {
    float4 b0 = *(const float4*)(b + l15 * 8);
    float4 b1 = *(const float4*)(b + l15 * 8 + 4);
    float4 o0 = make_float4(ax0 + b0.x, ay0 + b0.y, ax1 + b0.z, ay1 + b0.w);
    float4 o1 = make_float4(ax2 + b1.x, ay2 + b1.y, ax3 + b1.z, ay3 + b1.w);
    float* op = out + (size_t)node * OUT_C + l15 * 8;
    *(float4*)op = o0;
    *(float4*)(op + 4) = o1;
  }

  if (node == 0 && lane == 0) {
    for (int t = 0; t < tail; t++) out[(size_t)n * OUT_C + t] = 0.0f;
  }
}

extern "C" void kernel_launch(void* const* d_in, const int* in_sizes, int n_in,
                              void* d_out, int out_size, void* d_ws, size_t ws_size,
                              hipStream_t stream) {
  const float* x = (const float*)d_in[0];
  const int* ei = (const int*)d_in[1];
  const float* W = (const float*)d_in[2];
  const float* b = (const float*)d_in[3];

  const int n = in_sizes[0] / IN_C;
  const int E = in_sizes[1] / 2;
  const int* src = ei;
  const int* dst = ei + E;
  float* out = (float*)d_out;

  const int nchunks = cdiv(E, CHUNK);
  const int nbk = cdiv(n, 1024);

  size_t p = 0;
  auto alloc = [&](size_t bytes) { size_t o = p; p += (bytes + 255) & ~(size_t)255; return o; };
  char* ws = (char*)d_ws;
  float*          dinv   = (float*)(ws + alloc((size_t)n * 4));
  int*            offs   = (int*)(ws + alloc(((size_t)n + 1) * 4));
  int*            csrsrc = (int*)(ws + alloc((size_t)E * 4));
  int*            bstart = (int*)(ws + alloc((NB + 1) * 4));
  unsigned short* wfh    = (unsigned short*)(ws + alloc((size_t)IN_C * OUT_C * 2));
  unsigned short* wfl    = (unsigned short*)(ws + alloc((size_t)IN_C * OUT_C * 2));
  // union region: {inter + table} (CSR build) then reused as h2 (GEMM onward)
  size_t upos = p;
  int*            inter  = (int*)(ws + upos);
  int*            table  = (int*)(ws + upos + (((size_t)E * 4 + 255) & ~(size_t)255));
  unsigned short* h      = (unsigned short*)(ws + upos);

  wsplit_kernel<<<cdiv(IN_C * OUT_C, 256), 256, 0, stream>>>(W, wfh, wfl);
  hist_kernel<<<nchunks, 256, 0, stream>>>(dst, table, nchunks, E);
  tscan_kernel<<<1, 256, 0, stream>>>(table, bstart, nchunks, E);
  scat2_kernel<<<nchunks, 256, 0, stream>>>(src, dst, table, inter, nchunks, E);
  bdeg_offs_kernel<<<nbk, 256, 0, stream>>>(inter, bstart, offs, dinv, n, E, nbk);
  scat3_kernel<<<nbk, 256, 0, stream>>>(inter, bstart, offs, csrsrc, n);
  gemm_mfma_kernel<<<cdiv(n, 128), 256, 0, stream>>>(x, wfh, wfl, dinv, h, n);
  int tail = out_size - n * OUT_C;
  gather_kernel<<<cdiv(n, 4), 256, 0, stream>>>(offs, csrsrc, h, dinv, b, out, n, tail);
}